// Round 5
// baseline (275.608 us; speedup 1.0000x reference)
//
#include <hip/hip_runtime.h>
#include <hip/hip_bf16.h>

#define NNODES 50000
#define NEDGES 300000
#define NGRAPH 2048
#define NFEAT  128
#define NHID   256
#define DOUT   32
#define NROWS  50048   // 64-aligned row allocation

typedef __bf16 bf16x8 __attribute__((ext_vector_type(8)));
typedef float  f32x4  __attribute__((ext_vector_type(4)));
typedef unsigned short ushort8v __attribute__((ext_vector_type(8)));
typedef __attribute__((address_space(1))) const void* gas_ptr;
typedef __attribute__((address_space(3))) void* las_ptr;

__device__ __forceinline__ float bf2f(unsigned short u) {
    return __uint_as_float(((unsigned)u) << 16);
}
__device__ __forceinline__ unsigned short f2bf(float f) {
    unsigned u = __float_as_uint(f);
    unsigned r = u + 0x7FFFu + ((u >> 16) & 1u);   // RNE
    return (unsigned short)(r >> 16);
}
__device__ __forceinline__ float sb2f(unsigned v, int k) {   // signed byte k of word -> float
    return (float)((signed char)(v >> (8 * k)));
}

// Activation arrays consumed by GEMM staging (X16, Za, Zb) are stored XOR-swizzled:
// 16B chunk ch of row r lives at chunk index (ch ^ (r&7)). Gather-side activations for
// layers 2-3 (Hq) are per-row int8 + f32 scale (csc). Pooling is fused into gemm3's
// epilogue (batch-sorted rows -> per-column run-length walk + f32 atomics into HGacc).

// ---------- prep: cast x -> bf16 (swizzled), weights -> bf16, zero cnt/fill/adj8/HGacc ----
__global__ __launch_bounds__(256) void prep_k(const float* __restrict__ x, unsigned short* __restrict__ x16,
                                              const float* __restrict__ W1, const float* __restrict__ W2,
                                              const float* __restrict__ W3, const float* __restrict__ Wf1,
                                              const float* __restrict__ Wf2,
                                              unsigned short* __restrict__ Wt1, unsigned short* __restrict__ Wt2,
                                              unsigned short* __restrict__ Wt3, unsigned short* __restrict__ Wf1t,
                                              unsigned short* __restrict__ Wf2t,
                                              int* __restrict__ cnt, int* __restrict__ fill,
                                              int4* __restrict__ adj8z, float4* __restrict__ hgz) {
    int idx = blockIdx.x * 256 + threadIdx.x;
    if (idx < 800000) {                       // x cast, one 16B chunk/thread, swizzled store
        int i = idx * 8;
        float4 a = *(const float4*)&x[i];
        float4 b = *(const float4*)&x[i + 4];
        ushort8v o = { f2bf(a.x), f2bf(a.y), f2bf(a.z), f2bf(a.w),
                       f2bf(b.x), f2bf(b.y), f2bf(b.z), f2bf(b.w) };
        int row = idx >> 4, ch = idx & 15;
        ((ushort8v*)x16)[(size_t)(row << 4) | (ch ^ (row & 7))] = o;
        return;
    }
    int t = idx - 800000;
    if (t < 200704) {
        const float* W; unsigned short* Wt; int K, N, base; bool sw;
        if      (t <  32768) { W = W1;  Wt = Wt1;  K = 128; N = 256; base = 0;      sw = true; }
        else if (t <  98304) { W = W2;  Wt = Wt2;  K = 256; N = 256; base = 32768;  sw = true; }
        else if (t < 163840) { W = W3;  Wt = Wt3;  K = 256; N = 256; base = 98304;  sw = true; }
        else if (t < 196608) { W = Wf1; Wt = Wf1t; K = 256; N = 128; base = 163840; sw = false; }
        else                 { W = Wf2; Wt = Wf2t; K = 128; N = 32;  base = 196608; sw = false; }
        int i = t - base; int n = i / K, k = i - n * K;
        unsigned short v = f2bf(W[(size_t)k * N + n]);
        if (sw) Wt[(k >> 5) * 8192 + n * 32 + (k & 31)] = v;   // sliced layout (N=256)
        else    Wt[i] = v;                                      // row-major [n][K]
        return;
    }
    t -= 200704;
    if (t < NNODES) { cnt[t] = 0; fill[t] = 0; return; }
    t -= NNODES;
    if (t < 200000) { int4 z4 = {0, 0, 0, 0}; adj8z[t] = z4; return; }   // zero inline slots
    t -= 200000;
    if (t < 131072) { hgz[t] = make_float4(0.f, 0.f, 0.f, 0.f); }        // zero HG accumulators
}

__global__ __launch_bounds__(256) void edge_hist_k(const int* __restrict__ dst, int* cnt, int E) {
    int e = blockIdx.x * 256 + threadIdx.x;
    if (e < E) atomicAdd(&cnt[dst[e]], 1);
}

// block-level scan + dinv + node header {deg, dinv^2} (chunk = 1024 nodes)
__global__ __launch_bounds__(1024) void scan_block_k(const int* __restrict__ cnt, int* __restrict__ rowp,
                                                     int* __restrict__ part, float* __restrict__ dinv,
                                                     int2* __restrict__ hdr, int n) {
    __shared__ int s[1024];
    int tid = threadIdx.x;
    int i = blockIdx.x * 1024 + tid;
    int v = (i < n) ? cnt[i] : 0;
    if (i < n) {
        float dv = rsqrtf((float)(v + 1));   // +1 self-loop
        dinv[i] = dv;
        hdr[i] = make_int2(v, __float_as_int(dv * dv));
    }
    s[tid] = v;
    __syncthreads();
    for (int off = 1; off < 1024; off <<= 1) {
        int t = (tid >= off) ? s[tid - off] : 0;
        __syncthreads();
        s[tid] += t;
        __syncthreads();
    }
    if (i < n) rowp[i] = s[tid] - v;               // exclusive, pre-offset
    if (tid == 1023) part[blockIdx.x] = s[1023];
}

// scatter: first 8 edges/dst -> inline slots adj8; rest -> CSR adj (entries >=8 only).
// rowp only read on the rare overflow path. Also finalizes rowp + graph-start table.
__global__ __launch_bounds__(256) void scatter_k(const int* __restrict__ src, const int* __restrict__ dst,
                                                 const int* __restrict__ rowp_pre, const int* __restrict__ part,
                                                 int* fill, const float* __restrict__ dinv,
                                                 int2* __restrict__ adj8, int2* __restrict__ adj,
                                                 int* __restrict__ rowp_fin,
                                                 const int* __restrict__ batch, int* __restrict__ gstart,
                                                 int E, int n, int nb) {
    __shared__ int s[64];
    int tid = threadIdx.x;
    if (tid < 64) s[tid] = (tid < nb) ? part[tid] : 0;
    __syncthreads();
    for (int off = 1; off < 64; off <<= 1) {
        int t = 0;
        if (tid < 64 && tid >= off) t = s[tid - off];
        __syncthreads();
        if (tid < 64) s[tid] += t;
        __syncthreads();
    }
    int gid = blockIdx.x * 256 + tid;
    if (gid <= n) {
        if (gid < n) {
            int ch = gid >> 10;
            int base = (ch == 0) ? 0 : s[ch - 1];
            rowp_fin[gid] = rowp_pre[gid] + base;
        } else {
            rowp_fin[n] = s[nb - 1];
        }
    }
    if (gid < n) {   // graph start offsets: gstart[g] = first node with batch >= g
        int b = batch[gid];
        int prev = (gid == 0) ? -1 : batch[gid - 1];
        for (int g = prev + 1; g <= b; ++g) gstart[g] = gid;
        if (gid == n - 1)
            for (int g = b + 1; g <= NGRAPH; ++g) gstart[g] = n;
    }
    if (gid < E) {
        int ss = src[gid], d = dst[gid];
        int f = atomicAdd(&fill[d], 1);
        int2 a; a.x = ss; a.y = __float_as_int(dinv[ss] * dinv[d]);
        if (f < 8) {
            adj8[d * 8 + f] = a;
        } else {
            int ch = d >> 10;
            int base = (ch == 0) ? 0 : s[ch - 1];
            adj[rowp_pre[d] + base + f] = a;
        }
    }
}

// ---------- slot-based aggregation, bf16 source (layer 1): z = A_hat @ T ----------
template<int CH>   // 16B chunks per row
__global__ __launch_bounds__(256) void agg_k(const unsigned short* __restrict__ T,
                                             const int4* __restrict__ adj8,
                                             const int2* __restrict__ hdr,
                                             const int* __restrict__ rowf,
                                             const int2* __restrict__ adj,
                                             unsigned short* __restrict__ z, int n) {
    int g  = threadIdx.x / CH;
    int li = threadIdx.x % CH;
    int node = blockIdx.x * (256 / CH) + g;
    if (node >= n) return;
    const ushort8v* tp = (const ushort8v*)T;
    int2 h = hdr[node];
    int deg = h.x;
    float sw = __int_as_float(h.y);
    ushort8v u = tp[(size_t)node * CH + (li ^ (node & 7))];
    int4 s4[4];
#pragma unroll
    for (int j = 0; j < 4; ++j) s4[j] = adj8[node * 4 + j];
    float ac[8];
#pragma unroll
    for (int k = 0; k < 8; ++k) ac[k] = bf2f(u[k]) * sw;
    int c[8]; float w[8];
#pragma unroll
    for (int j = 0; j < 4; ++j) {
        c[2 * j]     = s4[j].x; w[2 * j]     = __int_as_float(s4[j].y);
        c[2 * j + 1] = s4[j].z; w[2 * j + 1] = __int_as_float(s4[j].w);
    }
    ushort8v mm[8];
#pragma unroll
    for (int j = 0; j < 8; ++j) mm[j] = tp[(size_t)c[j] * CH + (li ^ (c[j] & 7))];
#pragma unroll
    for (int j = 0; j < 8; ++j)
#pragma unroll
        for (int k = 0; k < 8; ++k)
            ac[k] += bf2f(mm[j][k]) * w[j];
    if (deg > 8) {   // overflow: CSR entries >= 8
        int e0 = rowf[node], e1 = e0 + deg;
        for (int e = e0 + 8; e < e1; e += 4) {
            int2 a2[4];
#pragma unroll
            for (int j = 0; j < 4; ++j) {
                int ee = e + j;
                a2[j] = (ee < e1) ? adj[ee] : make_int2(0, 0);
            }
            ushort8v m2[4];
#pragma unroll
            for (int j = 0; j < 4; ++j) m2[j] = tp[(size_t)a2[j].x * CH + (li ^ (a2[j].x & 7))];
#pragma unroll
            for (int j = 0; j < 4; ++j)
#pragma unroll
                for (int k = 0; k < 8; ++k)
                    ac[k] += bf2f(m2[j][k]) * __int_as_float(a2[j].y);
        }
    }
    ushort8v o;
#pragma unroll
    for (int k = 0; k < 8; ++k) o[k] = f2bf(ac[k]);
    ((ushort8v*)z)[(size_t)node * CH + (li ^ (node & 7))] = o;
}

// ---------- slot-based aggregation, int8 source (layers 2-3), 16 lanes/node ----------
// uint4 (16B) per lane -> half the VMEM instructions of the 32-lane/8B variant and
// 4 rows in flight per wave. Output z is bf16 swizzled (GEMM A operand stays bf16).
__global__ __launch_bounds__(256) void agg_q_k(const unsigned char* __restrict__ Hq,
                                               const float* __restrict__ csc,
                                               const int4* __restrict__ adj8,
                                               const int2* __restrict__ hdr,
                                               const int* __restrict__ rowf,
                                               const int2* __restrict__ adj,
                                               unsigned short* __restrict__ z, int n) {
    int g  = threadIdx.x >> 4;
    int li = threadIdx.x & 15;
    int node = blockIdx.x * 16 + g;
    if (node >= n) return;
    const uint4* qp = (const uint4*)Hq;       // 16B chunks (16 per row)
    int2 h = hdr[node];
    int deg = h.x;
    float swgt = __int_as_float(h.y) * csc[node];
    uint4 u = qp[(size_t)node * 16 + li];
    int4 s4[4];
#pragma unroll
    for (int j = 0; j < 4; ++j) s4[j] = adj8[node * 4 + j];
    int c[8]; float w[8];
#pragma unroll
    for (int j = 0; j < 4; ++j) {
        c[2 * j]     = s4[j].x; w[2 * j]     = __int_as_float(s4[j].y);
        c[2 * j + 1] = s4[j].z; w[2 * j + 1] = __int_as_float(s4[j].w);
    }
    uint4 mm[8];
#pragma unroll
    for (int j = 0; j < 8; ++j) mm[j] = qp[(size_t)c[j] * 16 + li];
    float ws[8];
#pragma unroll
    for (int j = 0; j < 8; ++j) ws[j] = w[j] * csc[c[j]];
    float ac[16];
#pragma unroll
    for (int k = 0; k < 4; ++k) {
        ac[k]      = sb2f(u.x, k) * swgt;
        ac[k + 4]  = sb2f(u.y, k) * swgt;
        ac[k + 8]  = sb2f(u.z, k) * swgt;
        ac[k + 12] = sb2f(u.w, k) * swgt;
    }
#pragma unroll
    for (int j = 0; j < 8; ++j)
#pragma unroll
        for (int k = 0; k < 4; ++k) {
            ac[k]      += sb2f(mm[j].x, k) * ws[j];
            ac[k + 4]  += sb2f(mm[j].y, k) * ws[j];
            ac[k + 8]  += sb2f(mm[j].z, k) * ws[j];
            ac[k + 12] += sb2f(mm[j].w, k) * ws[j];
        }
    if (deg > 8) {   // overflow: CSR entries >= 8
        int e0 = rowf[node], e1 = e0 + deg;
        for (int e = e0 + 8; e < e1; e += 4) {
            int2 a2[4];
#pragma unroll
            for (int j = 0; j < 4; ++j) {
                int ee = e + j;
                a2[j] = (ee < e1) ? adj[ee] : make_int2(0, 0);
            }
            uint4 m2[4]; float w2[4];
#pragma unroll
            for (int j = 0; j < 4; ++j) m2[j] = qp[(size_t)a2[j].x * 16 + li];
#pragma unroll
            for (int j = 0; j < 4; ++j) w2[j] = __int_as_float(a2[j].y) * csc[a2[j].x];
#pragma unroll
            for (int j = 0; j < 4; ++j)
#pragma unroll
                for (int k = 0; k < 4; ++k) {
                    ac[k]      += sb2f(m2[j].x, k) * w2[j];
                    ac[k + 4]  += sb2f(m2[j].y, k) * w2[j];
                    ac[k + 8]  += sb2f(m2[j].z, k) * w2[j];
                    ac[k + 12] += sb2f(m2[j].w, k) * w2[j];
                }
        }
    }
    ushort8v o0, o1;
#pragma unroll
    for (int k = 0; k < 8; ++k) { o0[k] = f2bf(ac[k]); o1[k] = f2bf(ac[k + 8]); }
    size_t base = (size_t)node * 32;
    ((ushort8v*)z)[base + ((2 * li)     ^ (node & 7))] = o0;
    ((ushort8v*)z)[base + ((2 * li + 1) ^ (node & 7))] = o1;
}

// ---------- MFMA GEMM: DMA-staged swizzled A-tile + register-stationary B ----------
// MODE 1: epilogue emits per-row int8 + f32 scale (for the next gather).
// MODE 2: epilogue fuses global mean pooling (run-length walk over batch-sorted rows
//         + f32 atomics into HGacc); no activation store at all.
template<int K, int MODE>
__global__ __launch_bounds__(512, 2) void gemm_k(const unsigned short* __restrict__ A,
                                                 const unsigned short* __restrict__ Bsw,
                                                 const float* __restrict__ bias,
                                                 unsigned char* __restrict__ Cq,
                                                 float* __restrict__ csc,
                                                 float* __restrict__ HGacc,
                                                 const int* __restrict__ batch,
                                                 int M, int flags, int ntiles) {
    constexpr int CPR = K / 8;                 // 16B chunks per row
    constexpr int LP  = (64 * CPR) / 512;      // staging issues per thread (2 or 4)
    __shared__ unsigned short At[64 * K];      // swizzled A tile (16/32 KB)
    __shared__ unsigned short Et[64 * 264];    // epilogue tile (33.8 KB)
    __shared__ int sbatch[64];
    const int tid = threadIdx.x;
    const int lane = tid & 63;
    const int wave = tid >> 6;                 // 0..7
    const int m = lane & 15, q = lane >> 4;
    const int wr = (wave >> 2) * 32;           // 0 / 32
    const int wc = (wave & 3) * 64;            // 0 / 64 / 128 / 192

    // load this wave's B slice (64 cols x K) into registers once
    bf16x8 breg[K / 32][4];
#pragma unroll
    for (int kt = 0; kt < K / 32; ++kt)
#pragma unroll
        for (int j = 0; j < 4; ++j)
            breg[kt][j] = *(const bf16x8*)&Bsw[kt * 8192 + (wc + j * 16 + m) * 32 + q * 8];

    for (int t = blockIdx.x; t < ntiles; t += gridDim.x) {
        const size_t cbase = (size_t)t * 64 * CPR;   // tile base (16B-chunk units)
        // stage A-tile: linear byte copy of the pre-swizzled global rows
#pragma unroll
        for (int p = 0; p < LP; ++p) {
            int u = p * 512 + tid;
            __builtin_amdgcn_global_load_lds((gas_ptr)(A + (cbase + u) * 8),
                                             (las_ptr)&At[(p * 512 + wave * 64) * 8], 16, 0, 0);
        }
        __syncthreads();   // staging complete (also orders vs prev tile's At/Et use)

        f32x4 acc[2][4] = {};
#pragma unroll
        for (int kt = 0; kt < K / 32; ++kt) {
            bf16x8 af[2];
#pragma unroll
            for (int i = 0; i < 2; ++i) {
                int lr = wr + i * 16 + m;
                af[i] = *(const bf16x8*)&At[(lr * CPR + ((kt * 4 + q) ^ (lr & 7))) * 8];
            }
#pragma unroll
            for (int i = 0; i < 2; ++i)
#pragma unroll
                for (int j = 0; j < 4; ++j)
                    acc[i][j] = __builtin_amdgcn_mfma_f32_16x16x32_bf16(af[i], breg[kt][j], acc[i][j], 0, 0, 0);
        }

        // epilogue: repack to Et (bias+relu applied)
#pragma unroll
        for (int i = 0; i < 2; ++i) {
#pragma unroll
            for (int j = 0; j < 4; ++j) {
                int c = wc + j * 16 + m;
                float bv = (flags & 2) ? bias[c] : 0.f;
#pragma unroll
                for (int r = 0; r < 4; ++r) {
                    float v = acc[i][j][r] + bv;
                    if (flags & 1) v = fmaxf(v, 0.f);
                    Et[(wr + i * 16 + q * 4 + r) * 264 + c] = f2bf(v);
                }
            }
        }
        if (MODE == 2 && tid < 64) {
            int rr = t * 64 + tid;
            sbatch[tid] = (rr < M) ? batch[rr] : -1;
        }
        __syncthreads();   // Et (and sbatch) ready; all At reads this tile complete

        if (MODE == 1) {
            // per-row int8 quantization: 8 threads/row, 32 elems/thread
            int row = tid >> 3, ch8 = tid & 7;
            int rr = t * 64 + row;
            ushort8v e[4];
#pragma unroll
            for (int k2 = 0; k2 < 4; ++k2)
                e[k2] = *(const ushort8v*)&Et[row * 264 + ch8 * 32 + k2 * 8];
            float mx = 0.f;
#pragma unroll
            for (int k2 = 0; k2 < 4; ++k2)
#pragma unroll
                for (int k = 0; k < 8; ++k) mx = fmaxf(mx, fabsf(bf2f(e[k2][k])));
            mx = fmaxf(mx, __shfl_xor(mx, 1, 64));
            mx = fmaxf(mx, __shfl_xor(mx, 2, 64));
            mx = fmaxf(mx, __shfl_xor(mx, 4, 64));
            float inv = (mx > 0.f) ? 127.f / mx : 0.f;
            unsigned pk[8];
#pragma unroll
            for (int w2 = 0; w2 < 8; ++w2) {
                unsigned p = 0;
#pragma unroll
                for (int b = 0; b < 4; ++b) {
                    int e8 = w2 * 4 + b;
                    float v = bf2f(e[e8 >> 3][e8 & 7]);
                    int qv = (int)rintf(v * inv);
                    p |= ((unsigned)(qv & 255)) << (8 * b);
                }
                pk[w2] = p;
            }
            if (rr < M) {
                uint4* dst = (uint4*)&Cq[(size_t)rr * 256 + ch8 * 32];
                dst[0] = make_uint4(pk[0], pk[1], pk[2], pk[3]);
                dst[1] = make_uint4(pk[4], pk[5], pk[6], pk[7]);
                if (ch8 == 0) csc[rr] = mx * (1.f / 127.f);
            }
        } else {
            // fused mean-pool: per-column run-length walk over 32 rows, atomic flush
            int c = tid & 255, hh = tid >> 8;
            int gcur = sbatch[hh * 32];
            float acp = 0.f;
#pragma unroll 1
            for (int r = 0; r < 32; ++r) {
                int gb = sbatch[hh * 32 + r];
                if (gb != gcur) {
                    if (gcur >= 0) atomicAdd(&HGacc[(size_t)gcur * 256 + c], acp);
                    acp = 0.f; gcur = gb;
                }
                if (gb >= 0) acp += bf2f(Et[(hh * 32 + r) * 264 + c]);
            }
            if (gcur >= 0) atomicAdd(&HGacc[(size_t)gcur * 256 + c], acp);
        }
    }
}

// ---------- MLP head: A from HGacc f32 (scale by 1/cnt, cast) ; rest as before ----------
__global__ __launch_bounds__(256) void mlp_head_k(const float* __restrict__ HGacc,
                                                  const int* __restrict__ gstart,
                                                  const unsigned short* __restrict__ Wf1t,  // [128][256]
                                                  const unsigned short* __restrict__ Wf2t,  // [32][128]
                                                  const float* __restrict__ bf1, const float* __restrict__ bf2,
                                                  float* __restrict__ out) {
    __shared__ unsigned short As1[128 * 32];   // 8 KB
    __shared__ unsigned short Bs1[128 * 32];   // 8 KB
    __shared__ unsigned short R[128 * 128];    // 32 KB
    __shared__ unsigned short Bs2[32 * 128];   // 8 KB
    __shared__ float invc[128];
    const int tid = threadIdx.x;
    const int lane = tid & 63, wave = tid >> 6;
    const int m = lane & 15, q = lane >> 4;
    const int rowBase = blockIdx.x * 128;
    const int wr = (wave >> 1) * 64;
    const int wc = (wave & 1) * 64;

#pragma unroll
    for (int c2 = 0; c2 < 2; ++c2) {
        const unsigned short* g = &Wf2t[(c2 * 256 + tid) * 8];
        __builtin_amdgcn_global_load_lds((gas_ptr)g, (las_ptr)&Bs2[(c2 * 256 + wave * 64) * 8], 16, 0, 0);
    }
    if (tid < 128) {
        int g0 = rowBase + tid;
        invc[tid] = 1.f / fmaxf((float)(gstart[g0 + 1] - gstart[g0]), 1.f);
    }
    __syncthreads();

    f32x4 acc[4][4] = {};
    for (int kt = 0; kt < 256; kt += 32) {
        {   // A-staging: f32 mean -> bf16, via registers + ds_write
            int row = tid >> 1, half = tid & 1;
            const float4* src = (const float4*)&HGacc[(size_t)(rowBase + row) * 256 + kt + half * 16];
            float4 f0 = src[0], f1 = src[1], f2 = src[2], f3 = src[3];
            float sc = invc[row];
            ushort8v p0 = { f2bf(f0.x * sc), f2bf(f0.y * sc), f2bf(f0.z * sc), f2bf(f0.w * sc),
                            f2bf(f1.x * sc), f2bf(f1.y * sc), f2bf(f1.z * sc), f2bf(f1.w * sc) };
            ushort8v p1 = { f2bf(f2.x * sc), f2bf(f2.y * sc), f2bf(f2.z * sc), f2bf(f2.w * sc),
                            f2bf(f3.x * sc), f2bf(f3.y * sc), f2bf(f3.z * sc), f2bf(f3.w * sc) };
            *(ushort8v*)&As1[row * 32 + half * 16] = p0;
            *(ushort8v*)&As1[row * 32 + half * 16 + 8] = p1;
        }
#pragma unroll
        for (int c2 = 0; c2 < 2; ++c2) {
            int u = c2 * 256 + tid;
            int row = u >> 2, kp = u & 3;
            const unsigned short* gb = &Wf1t[(size_t)row * 256 + kt + kp * 8];
            __builtin_amdgcn_global_load_lds((gas_ptr)gb, (las_ptr)&Bs1[(c2 * 256 + wave * 64) * 8], 16, 0, 0);
        }
        __syncthreads();
        bf16x8 af[4], bfr[4];
#pragma unroll
        for (int i = 0; i < 4; ++i) af[i] = *(const bf16x8*)&As1[(wr + i * 16 + m) * 32 + q * 8];
#pragma unroll
        for (int j = 0; j < 4; ++j) bfr[j] = *(const bf16x8*)&Bs1[(wc + j * 16 + m) * 32 + q * 8];
#pragma unroll
        for (int i = 0; i < 4; ++i)
#pragma unroll
            for (int j = 0; j < 4; ++j)
                acc[i][j] = __builtin_amdgcn_mfma_f32_16x16x32_bf16(af[i], bfr[j], acc[i][j], 0, 0, 0);
        __syncthreads();
    }
#pragma unroll
    for (int i = 0; i < 4; ++i)
#pragma unroll
        for (int j = 0; j < 4; ++j) {
            int c = wc + j * 16 + m;
            float bv = bf1[c];
#pragma unroll
            for (int r = 0; r < 4; ++r) {
                int rr = wr + i * 16 + q * 4 + r;
                R[rr * 128 + c] = f2bf(fmaxf(acc[i][j][r] + bv, 0.f));
            }
        }
    __syncthreads();

    const int wr2 = wave * 32;
    f32x4 acc2[2][2] = {};
#pragma unroll
    for (int s2 = 0; s2 < 4; ++s2) {
        bf16x8 af2[2], bf22[2];
#pragma unroll
        for (int i = 0; i < 2; ++i) af2[i] = *(const bf16x8*)&R[(wr2 + i * 16 + m) * 128 + s2 * 32 + q * 8];
#pragma unroll
        for (int ct = 0; ct < 2; ++ct) bf22[ct] = *(const bf16x8*)&Bs2[(ct * 16 + m) * 128 + s2 * 32 + q * 8];
#pragma unroll
        for (int i = 0; i < 2; ++i)
#pragma unroll
            for (int ct = 0; ct < 2; ++ct)
                acc2[i][ct] = __builtin_amdgcn_mfma_f32_16x16x32_bf16(af2[i], bf22[ct], acc2[i][ct], 0, 0, 0);
    }
#pragma unroll
    for (int i = 0; i < 2; ++i)
#pragma unroll
        for (int ct = 0; ct < 2; ++ct) {
            int c = ct * 16 + m;
            float bv = bf2[c];
#pragma unroll
            for (int r = 0; r < 4; ++r) {
                int rr = rowBase + wr2 + i * 16 + q * 4 + r;
                out[(size_t)rr * 32 + c] = acc2[i][ct][r] + bv;
            }
        }
}

extern "C" void kernel_launch(void* const* d_in, const int* in_sizes, int n_in,
                              void* d_out, int out_size, void* d_ws, size_t ws_size,
                              hipStream_t stream) {
    const float* x    = (const float*)d_in[0];
    const int*   ei   = (const int*)d_in[1];
    const int*   batch= (const int*)d_in[2];
    const float* W1   = (const float*)d_in[3];
    const float* b1   = (const float*)d_in[4];
    const float* W2   = (const float*)d_in[5];
    const float* b2   = (const float*)d_in[6];
    const float* W3   = (const float*)d_in[7];
    const float* b3   = (const float*)d_in[8];
    const float* Wf1  = (const float*)d_in[9];
    const float* bf1  = (const float*)d_in[10];
    const float* Wf2  = (const float*)d_in[11];
    const float* bf2  = (const float*)d_in[12];
    float* out = (float*)d_out;

    const int* e_src = ei;
    const int* e_dst = ei + NEDGES;

    char* ws = (char*)d_ws;
    size_t off = 0;
    auto alloc = [&](size_t bytes) -> void* {
        void* p = (void*)(ws + off);
        off += (bytes + 255) & ~(size_t)255;
        return p;
    };
    unsigned short* X16 = (unsigned short*)alloc((size_t)NROWS * NFEAT * 2);
    unsigned short* Za  = (unsigned short*)alloc((size_t)NROWS * NFEAT * 2);   // agg out, layer 1
    unsigned short* Zb  = (unsigned short*)alloc((size_t)NROWS * NHID * 2);    // agg out, layers 2-3
    unsigned char*  Hq  = (unsigned char*)alloc((size_t)NROWS * NHID);         // int8 activations
    float*          csc = (float*)alloc((size_t)NROWS * 4);                    // row scales
    float*          HGacc = (float*)alloc((size_t)NGRAPH * NHID * 4);          // pooled sums (f32)
    unsigned short* Wt1 = (unsigned short*)alloc((size_t)NHID * NFEAT * 2);    // sliced [4][256][32]
    unsigned short* Wt2 = (unsigned short*)alloc((size_t)NHID * NHID * 2);     // sliced [8][256][32]
    unsigned short* Wt3 = (unsigned short*)alloc((size_t)NHID * NHID * 2);     // sliced [8][256][32]
    unsigned short* Wf1t= (unsigned short*)alloc((size_t)NFEAT * NHID * 2);
    unsigned short* Wf2t= (unsigned short*)alloc((size_t)DOUT * NFEAT * 2);
    float* dinv = (float*)alloc((size_t)NNODES * 4);
    int*   cnt  = (int*)alloc((size_t)NNODES * 4);
    int*   fill = (int*)alloc((size_t)NNODES * 4);
    int*   rowp = (int*)alloc((size_t)(NNODES + 1) * 4);   // pre-offset
    int*   rowf = (int*)alloc((size_t)(NNODES + 1) * 4);   // finalized
    int2*  adj8 = (int2*)alloc((size_t)NNODES * 8 * 8);    // inline slots {src, norm} x8
    int2*  adj  = (int2*)alloc((size_t)NEDGES * 8);        // CSR overflow (entries >= 8)
    int2*  hdr  = (int2*)alloc((size_t)NNODES * 8);        // {deg, dinv^2}
    int*   part = (int*)alloc((size_t)64 * 4);
    int*   gstart = (int*)alloc((size_t)(NGRAPH + 1) * 4);
    (void)alloc(131072);   // tail pad

    const int nb = (NNODES + 1023) / 1024;   // 49

    // ---- prep: casts + zero cnt/fill/adj8/HGacc ----
    hipLaunchKernelGGL(prep_k, dim3((1381776 + 255) / 256), dim3(256), 0, stream,
                       x, X16, W1, W2, W3, Wf1, Wf2, Wt1, Wt2, Wt3, Wf1t, Wf2t, cnt, fill,
                       (int4*)adj8, (float4*)HGacc);
    // ---- CSR + slots + norm + graph starts ----
    hipLaunchKernelGGL(edge_hist_k, dim3((NEDGES + 255) / 256), dim3(256), 0, stream, e_dst, cnt, NEDGES);
    hipLaunchKernelGGL(scan_block_k, dim3(nb), dim3(1024), 0, stream, cnt, rowp, part, dinv, hdr, NNODES);
    hipLaunchKernelGGL(scatter_k, dim3((NEDGES + 255) / 256), dim3(256), 0, stream,
                       e_src, e_dst, rowp, part, fill, dinv, adj8, adj, rowf, batch, gstart,
                       NEDGES, NNODES, nb);

    const int ntiles = NROWS / 64;          // 782
    // ---- layer 1: Za = A_hat X (bf16); Hq,csc = q8(relu(Za@W1+b1)) ----
    hipLaunchKernelGGL((agg_k<16>), dim3((NNODES + 15) / 16), dim3(256), 0, stream,
                       X16, (const int4*)adj8, hdr, rowf, adj, Za, NNODES);
    hipLaunchKernelGGL((gemm_k<128, 1>), dim3(512), dim3(512), 0, stream,
                       Za, Wt1, b1, Hq, csc, (float*)nullptr, (const int*)nullptr, NNODES, 3, ntiles);
    // ---- layer 2: Zb = A_hat Hq (int8 gather); Hq,csc = q8(relu(Zb@W2+b2)) ----
    hipLaunchKernelGGL(agg_q_k, dim3((NNODES + 15) / 16), dim3(256), 0, stream,
                       Hq, csc, (const int4*)adj8, hdr, rowf, adj, Zb, NNODES);
    hipLaunchKernelGGL((gemm_k<256, 1>), dim3(512), dim3(512), 0, stream,
                       Zb, Wt2, b2, Hq, csc, (float*)nullptr, (const int*)nullptr, NNODES, 3, ntiles);
    // ---- layer 3: Zb = A_hat Hq; relu(Zb@W3+b3) pooled directly into HGacc ----
    hipLaunchKernelGGL(agg_q_k, dim3((NNODES + 15) / 16), dim3(256), 0, stream,
                       Hq, csc, (const int4*)adj8, hdr, rowf, adj, Zb, NNODES);
    hipLaunchKernelGGL((gemm_k<256, 2>), dim3(512), dim3(512), 0, stream,
                       Zb, Wt3, b3, (unsigned char*)nullptr, (float*)nullptr, HGacc, batch, NNODES, 3, ntiles);

    // ---- MLP head (mean + cast fused into A-staging) ----
    hipLaunchKernelGGL(mlp_head_k, dim3(NGRAPH / 128), dim3(256), 0, stream,
                       HGacc, gstart, Wf1t, Wf2t, bf1, bf2, out);
}

// Round 6
// 274.904 us; speedup vs baseline: 1.0026x; 1.0026x over previous
//
#include <hip/hip_runtime.h>
#include <hip/hip_bf16.h>

#define NNODES 50000
#define NEDGES 300000
#define NGRAPH 2048
#define NFEAT  128
#define NHID   256
#define DOUT   32
#define NROWS  50048   // 64-aligned row allocation

typedef __bf16 bf16x8 __attribute__((ext_vector_type(8)));
typedef float  f32x4  __attribute__((ext_vector_type(4)));
typedef unsigned short ushort8v __attribute__((ext_vector_type(8)));
typedef __attribute__((address_space(1))) const void* gas_ptr;
typedef __attribute__((address_space(3))) void* las_ptr;

__device__ __forceinline__ float bf2f(unsigned short u) {
    return __uint_as_float(((unsigned)u) << 16);
}
__device__ __forceinline__ unsigned short f2bf(float f) {
    unsigned u = __float_as_uint(f);
    unsigned r = u + 0x7FFFu + ((u >> 16) & 1u);   // RNE
    return (unsigned short)(r >> 16);
}
__device__ __forceinline__ float sb2f(unsigned v, int k) {   // signed byte k of word -> float
    return (float)((signed char)(v >> (8 * k)));
}

// GEMM-staged activations (Za, Zb) are bf16 XOR-swizzled (chunk ch of row r at index
// ch ^ (r&7)). ALL gather-side activations (Xq layer-1, Hq layers 2-3) are per-row
// int8 + f32 scale — halves random-gather traffic, the measured limiter. Pooling is
// fused into gemm3's epilogue (run-length walk + f32 atomics into HGacc).

// ---------- prep: quantize x -> int8/row-scale, weights -> bf16, zero cnt/fill/adj8/HGacc ----
__global__ __launch_bounds__(256) void prep_k(const float* __restrict__ x, unsigned char* __restrict__ Xq,
                                              float* __restrict__ xsc,
                                              const float* __restrict__ W1, const float* __restrict__ W2,
                                              const float* __restrict__ W3, const float* __restrict__ Wf1,
                                              const float* __restrict__ Wf2,
                                              unsigned short* __restrict__ Wt1, unsigned short* __restrict__ Wt2,
                                              unsigned short* __restrict__ Wt3, unsigned short* __restrict__ Wf1t,
                                              unsigned short* __restrict__ Wf2t,
                                              int* __restrict__ cnt, int* __restrict__ fill,
                                              int4* __restrict__ adj8z, float4* __restrict__ hgz) {
    int idx = blockIdx.x * 256 + threadIdx.x;
    if (idx < 800000) {                       // x quant: 16 threads/row, 8 elems/thread
        int row = idx >> 4, li = idx & 15;
        const float4* xs = (const float4*)&x[(size_t)row * 128 + li * 8];
        float4 a = xs[0], b = xs[1];
        float m = fmaxf(fmaxf(fmaxf(fabsf(a.x), fabsf(a.y)), fmaxf(fabsf(a.z), fabsf(a.w))),
                        fmaxf(fmaxf(fabsf(b.x), fabsf(b.y)), fmaxf(fabsf(b.z), fabsf(b.w))));
        m = fmaxf(m, __shfl_xor(m, 1, 16));
        m = fmaxf(m, __shfl_xor(m, 2, 16));
        m = fmaxf(m, __shfl_xor(m, 4, 16));
        m = fmaxf(m, __shfl_xor(m, 8, 16));
        float inv = (m > 0.f) ? 127.f / m : 0.f;
        float v[8] = {a.x, a.y, a.z, a.w, b.x, b.y, b.z, b.w};
        unsigned w0 = 0, w1 = 0;
#pragma unroll
        for (int k = 0; k < 4; ++k) {
            int q0 = (int)rintf(v[k] * inv);
            int q1 = (int)rintf(v[k + 4] * inv);
            w0 |= ((unsigned)(q0 & 255)) << (8 * k);
            w1 |= ((unsigned)(q1 & 255)) << (8 * k);
        }
        ((uint2*)Xq)[(size_t)row * 16 + li] = make_uint2(w0, w1);
        if (li == 0) xsc[row] = m * (1.f / 127.f);
        return;
    }
    int t = idx - 800000;
    if (t < 200704) {
        const float* W; unsigned short* Wt; int K, N, base; bool sw;
        if      (t <  32768) { W = W1;  Wt = Wt1;  K = 128; N = 256; base = 0;      sw = true; }
        else if (t <  98304) { W = W2;  Wt = Wt2;  K = 256; N = 256; base = 32768;  sw = true; }
        else if (t < 163840) { W = W3;  Wt = Wt3;  K = 256; N = 256; base = 98304;  sw = true; }
        else if (t < 196608) { W = Wf1; Wt = Wf1t; K = 256; N = 128; base = 163840; sw = false; }
        else                 { W = Wf2; Wt = Wf2t; K = 128; N = 32;  base = 196608; sw = false; }
        int i = t - base; int n = i / K, k = i - n * K;
        unsigned short v = f2bf(W[(size_t)k * N + n]);
        if (sw) Wt[(k >> 5) * 8192 + n * 32 + (k & 31)] = v;   // sliced layout (N=256)
        else    Wt[i] = v;                                      // row-major [n][K]
        return;
    }
    t -= 200704;
    if (t < NNODES) { cnt[t] = 0; fill[t] = 0; return; }
    t -= NNODES;
    if (t < 200000) { int4 z4 = {0, 0, 0, 0}; adj8z[t] = z4; return; }   // zero inline slots
    t -= 200000;
    if (t < 131072) { hgz[t] = make_float4(0.f, 0.f, 0.f, 0.f); }        // zero HG accumulators
}

__global__ __launch_bounds__(256) void edge_hist_k(const int* __restrict__ dst, int* cnt, int E) {
    int e = blockIdx.x * 256 + threadIdx.x;
    if (e < E) atomicAdd(&cnt[dst[e]], 1);
}

// block-level scan + dinv + node header {deg, dinv^2} (chunk = 1024 nodes)
__global__ __launch_bounds__(1024) void scan_block_k(const int* __restrict__ cnt, int* __restrict__ rowp,
                                                     int* __restrict__ part, float* __restrict__ dinv,
                                                     int2* __restrict__ hdr, int n) {
    __shared__ int s[1024];
    int tid = threadIdx.x;
    int i = blockIdx.x * 1024 + tid;
    int v = (i < n) ? cnt[i] : 0;
    if (i < n) {
        float dv = rsqrtf((float)(v + 1));   // +1 self-loop
        dinv[i] = dv;
        hdr[i] = make_int2(v, __float_as_int(dv * dv));
    }
    s[tid] = v;
    __syncthreads();
    for (int off = 1; off < 1024; off <<= 1) {
        int t = (tid >= off) ? s[tid - off] : 0;
        __syncthreads();
        s[tid] += t;
        __syncthreads();
    }
    if (i < n) rowp[i] = s[tid] - v;               // exclusive, pre-offset
    if (tid == 1023) part[blockIdx.x] = s[1023];
}

// scatter: first 8 edges/dst -> inline slots adj8; rest -> CSR adj (entries >=8 only).
// rowp only read on the rare overflow path. Also finalizes rowp + graph-start table.
__global__ __launch_bounds__(256) void scatter_k(const int* __restrict__ src, const int* __restrict__ dst,
                                                 const int* __restrict__ rowp_pre, const int* __restrict__ part,
                                                 int* fill, const float* __restrict__ dinv,
                                                 int2* __restrict__ adj8, int2* __restrict__ adj,
                                                 int* __restrict__ rowp_fin,
                                                 const int* __restrict__ batch, int* __restrict__ gstart,
                                                 int E, int n, int nb) {
    __shared__ int s[64];
    int tid = threadIdx.x;
    if (tid < 64) s[tid] = (tid < nb) ? part[tid] : 0;
    __syncthreads();
    for (int off = 1; off < 64; off <<= 1) {
        int t = 0;
        if (tid < 64 && tid >= off) t = s[tid - off];
        __syncthreads();
        if (tid < 64) s[tid] += t;
        __syncthreads();
    }
    int gid = blockIdx.x * 256 + tid;
    if (gid <= n) {
        if (gid < n) {
            int ch = gid >> 10;
            int base = (ch == 0) ? 0 : s[ch - 1];
            rowp_fin[gid] = rowp_pre[gid] + base;
        } else {
            rowp_fin[n] = s[nb - 1];
        }
    }
    if (gid < n) {   // graph start offsets: gstart[g] = first node with batch >= g
        int b = batch[gid];
        int prev = (gid == 0) ? -1 : batch[gid - 1];
        for (int g = prev + 1; g <= b; ++g) gstart[g] = gid;
        if (gid == n - 1)
            for (int g = b + 1; g <= NGRAPH; ++g) gstart[g] = n;
    }
    if (gid < E) {
        int ss = src[gid], d = dst[gid];
        int f = atomicAdd(&fill[d], 1);
        int2 a; a.x = ss; a.y = __float_as_int(dinv[ss] * dinv[d]);
        if (f < 8) {
            adj8[d * 8 + f] = a;
        } else {
            int ch = d >> 10;
            int base = (ch == 0) ? 0 : s[ch - 1];
            adj[rowp_pre[d] + base + f] = a;
        }
    }
}

// ---------- layer-1 aggregation: int8 X source (128B rows), 16 lanes/node, uint2/lane ----
__global__ __launch_bounds__(256) void agg_q1_k(const unsigned char* __restrict__ Xq,
                                                const float* __restrict__ xsc,
                                                const int4* __restrict__ adj8,
                                                const int2* __restrict__ hdr,
                                                const int* __restrict__ rowf,
                                                const int2* __restrict__ adj,
                                                unsigned short* __restrict__ z, int n) {
    int g  = threadIdx.x >> 4;
    int li = threadIdx.x & 15;
    int node = blockIdx.x * 16 + g;
    if (node >= n) return;
    const uint2* qp = (const uint2*)Xq;       // 8B chunks, 16 per row
    int2 h = hdr[node];
    int deg = h.x;
    float swgt = __int_as_float(h.y) * xsc[node];
    uint2 u = qp[(size_t)node * 16 + li];
    int4 s4[4];
#pragma unroll
    for (int j = 0; j < 4; ++j) s4[j] = adj8[node * 4 + j];
    int c[8]; float w[8];
#pragma unroll
    for (int j = 0; j < 4; ++j) {
        c[2 * j]     = s4[j].x; w[2 * j]     = __int_as_float(s4[j].y);
        c[2 * j + 1] = s4[j].z; w[2 * j + 1] = __int_as_float(s4[j].w);
    }
    uint2 mm[8];
#pragma unroll
    for (int j = 0; j < 8; ++j) mm[j] = qp[(size_t)c[j] * 16 + li];
    float ws[8];
#pragma unroll
    for (int j = 0; j < 8; ++j) ws[j] = w[j] * xsc[c[j]];
    float ac[8];
#pragma unroll
    for (int k = 0; k < 4; ++k) {
        ac[k]     = sb2f(u.x, k) * swgt;
        ac[k + 4] = sb2f(u.y, k) * swgt;
    }
#pragma unroll
    for (int j = 0; j < 8; ++j)
#pragma unroll
        for (int k = 0; k < 4; ++k) {
            ac[k]     += sb2f(mm[j].x, k) * ws[j];
            ac[k + 4] += sb2f(mm[j].y, k) * ws[j];
        }
    if (deg > 8) {   // overflow: CSR entries >= 8
        int e0 = rowf[node], e1 = e0 + deg;
        for (int e = e0 + 8; e < e1; e += 4) {
            int2 a2[4];
#pragma unroll
            for (int j = 0; j < 4; ++j) {
                int ee = e + j;
                a2[j] = (ee < e1) ? adj[ee] : make_int2(0, 0);
            }
            uint2 m2[4]; float w2[4];
#pragma unroll
            for (int j = 0; j < 4; ++j) m2[j] = qp[(size_t)a2[j].x * 16 + li];
#pragma unroll
            for (int j = 0; j < 4; ++j) w2[j] = __int_as_float(a2[j].y) * xsc[a2[j].x];
#pragma unroll
            for (int j = 0; j < 4; ++j)
#pragma unroll
                for (int k = 0; k < 4; ++k) {
                    ac[k]     += sb2f(m2[j].x, k) * w2[j];
                    ac[k + 4] += sb2f(m2[j].y, k) * w2[j];
                }
        }
    }
    ushort8v o;
#pragma unroll
    for (int k = 0; k < 8; ++k) o[k] = f2bf(ac[k]);
    ((ushort8v*)z)[(size_t)node * 16 + (li ^ (node & 7))] = o;   // 16B chunk li of Za row
}

// ---------- layers 2-3 aggregation: int8 source (256B rows), 32 lanes/node, uint2/lane ----
__global__ __launch_bounds__(256) void agg_q_k(const unsigned char* __restrict__ Hq,
                                               const float* __restrict__ csc,
                                               const int4* __restrict__ adj8,
                                               const int2* __restrict__ hdr,
                                               const int* __restrict__ rowf,
                                               const int2* __restrict__ adj,
                                               unsigned short* __restrict__ z, int n) {
    int g  = threadIdx.x >> 5;
    int li = threadIdx.x & 31;
    int node = blockIdx.x * 8 + g;
    if (node >= n) return;
    const uint2* qp = (const uint2*)Hq;       // 8B chunks, 32 per row
    int2 h = hdr[node];
    int deg = h.x;
    float swgt = __int_as_float(h.y) * csc[node];
    uint2 u = qp[(size_t)node * 32 + li];
    int4 s4[4];
#pragma unroll
    for (int j = 0; j < 4; ++j) s4[j] = adj8[node * 4 + j];
    int c[8]; float w[8];
#pragma unroll
    for (int j = 0; j < 4; ++j) {
        c[2 * j]     = s4[j].x; w[2 * j]     = __int_as_float(s4[j].y);
        c[2 * j + 1] = s4[j].z; w[2 * j + 1] = __int_as_float(s4[j].w);
    }
    uint2 mm[8];
#pragma unroll
    for (int j = 0; j < 8; ++j) mm[j] = qp[(size_t)c[j] * 32 + li];
    float ws[8];
#pragma unroll
    for (int j = 0; j < 8; ++j) ws[j] = w[j] * csc[c[j]];
    float ac[8];
#pragma unroll
    for (int k = 0; k < 4; ++k) {
        ac[k]     = sb2f(u.x, k) * swgt;
        ac[k + 4] = sb2f(u.y, k) * swgt;
    }
#pragma unroll
    for (int j = 0; j < 8; ++j)
#pragma unroll
        for (int k = 0; k < 4; ++k) {
            ac[k]     += sb2f(mm[j].x, k) * ws[j];
            ac[k + 4] += sb2f(mm[j].y, k) * ws[j];
        }
    if (deg > 8) {   // overflow: CSR entries >= 8
        int e0 = rowf[node], e1 = e0 + deg;
        for (int e = e0 + 8; e < e1; e += 4) {
            int2 a2[4];
#pragma unroll
            for (int j = 0; j < 4; ++j) {
                int ee = e + j;
                a2[j] = (ee < e1) ? adj[ee] : make_int2(0, 0);
            }
            uint2 m2[4]; float w2[4];
#pragma unroll
            for (int j = 0; j < 4; ++j) m2[j] = qp[(size_t)a2[j].x * 32 + li];
#pragma unroll
            for (int j = 0; j < 4; ++j) w2[j] = __int_as_float(a2[j].y) * csc[a2[j].x];
#pragma unroll
            for (int j = 0; j < 4; ++j)
#pragma unroll
                for (int k = 0; k < 4; ++k) {
                    ac[k]     += sb2f(m2[j].x, k) * w2[j];
                    ac[k + 4] += sb2f(m2[j].y, k) * w2[j];
                }
        }
    }
    ushort8v o;
#pragma unroll
    for (int k = 0; k < 8; ++k) o[k] = f2bf(ac[k]);
    ((ushort8v*)z)[(size_t)node * 32 + (li ^ (node & 7))] = o;
}

// ---------- MFMA GEMM: DMA-staged swizzled A-tile + register-stationary B ----------
// MODE 1: epilogue emits per-row int8 + f32 scale (for the next gather).
// MODE 2: epilogue fuses global mean pooling (run-length walk over batch-sorted rows
//         + f32 atomics into HGacc); no activation store at all.
template<int K, int MODE>
__global__ __launch_bounds__(512, 2) void gemm_k(const unsigned short* __restrict__ A,
                                                 const unsigned short* __restrict__ Bsw,
                                                 const float* __restrict__ bias,
                                                 unsigned char* __restrict__ Cq,
                                                 float* __restrict__ csc,
                                                 float* __restrict__ HGacc,
                                                 const int* __restrict__ batch,
                                                 int M, int flags, int ntiles) {
    constexpr int CPR = K / 8;                 // 16B chunks per row
    constexpr int LP  = (64 * CPR) / 512;      // staging issues per thread (2 or 4)
    __shared__ unsigned short At[64 * K];      // swizzled A tile (16/32 KB)
    __shared__ unsigned short Et[64 * 264];    // epilogue tile (33.8 KB)
    __shared__ int sbatch[64];
    const int tid = threadIdx.x;
    const int lane = tid & 63;
    const int wave = tid >> 6;                 // 0..7
    const int m = lane & 15, q = lane >> 4;
    const int wr = (wave >> 2) * 32;           // 0 / 32
    const int wc = (wave & 3) * 64;            // 0 / 64 / 128 / 192

    // load this wave's B slice (64 cols x K) into registers once
    bf16x8 breg[K / 32][4];
#pragma unroll
    for (int kt = 0; kt < K / 32; ++kt)
#pragma unroll
        for (int j = 0; j < 4; ++j)
            breg[kt][j] = *(const bf16x8*)&Bsw[kt * 8192 + (wc + j * 16 + m) * 32 + q * 8];

    for (int t = blockIdx.x; t < ntiles; t += gridDim.x) {
        const size_t cbase = (size_t)t * 64 * CPR;   // tile base (16B-chunk units)
        // stage A-tile: linear byte copy of the pre-swizzled global rows
#pragma unroll
        for (int p = 0; p < LP; ++p) {
            int u = p * 512 + tid;
            __builtin_amdgcn_global_load_lds((gas_ptr)(A + (cbase + u) * 8),
                                             (las_ptr)&At[(p * 512 + wave * 64) * 8], 16, 0, 0);
        }
        __syncthreads();   // staging complete (also orders vs prev tile's At/Et use)

        f32x4 acc[2][4] = {};
#pragma unroll
        for (int kt = 0; kt < K / 32; ++kt) {
            bf16x8 af[2];
#pragma unroll
            for (int i = 0; i < 2; ++i) {
                int lr = wr + i * 16 + m;
                af[i] = *(const bf16x8*)&At[(lr * CPR + ((kt * 4 + q) ^ (lr & 7))) * 8];
            }
#pragma unroll
            for (int i = 0; i < 2; ++i)
#pragma unroll
                for (int j = 0; j < 4; ++j)
                    acc[i][j] = __builtin_amdgcn_mfma_f32_16x16x32_bf16(af[i], breg[kt][j], acc[i][j], 0, 0, 0);
        }

        // epilogue: repack to Et (bias+relu applied)
#pragma unroll
        for (int i = 0; i < 2; ++i) {
#pragma unroll
            for (int j = 0; j < 4; ++j) {
                int c = wc + j * 16 + m;
                float bv = (flags & 2) ? bias[c] : 0.f;
#pragma unroll
                for (int r = 0; r < 4; ++r) {
                    float v = acc[i][j][r] + bv;
                    if (flags & 1) v = fmaxf(v, 0.f);
                    Et[(wr + i * 16 + q * 4 + r) * 264 + c] = f2bf(v);
                }
            }
        }
        if (MODE == 2 && tid < 64) {
            int rr = t * 64 + tid;
            sbatch[tid] = (rr < M) ? batch[rr] : -1;
        }
        __syncthreads();   // Et (and sbatch) ready; all At reads this tile complete

        if (MODE == 1) {
            // per-row int8 quantization: 8 threads/row, 32 elems/thread
            int row = tid >> 3, ch8 = tid & 7;
            int rr = t * 64 + row;
            ushort8v e[4];
#pragma unroll
            for (int k2 = 0; k2 < 4; ++k2)
                e[k2] = *(const ushort8v*)&Et[row * 264 + ch8 * 32 + k2 * 8];
            float mx = 0.f;
#pragma unroll
            for (int k2 = 0; k2 < 4; ++k2)
#pragma unroll
                for (int k = 0; k < 8; ++k) mx = fmaxf(mx, fabsf(bf2f(e[k2][k])));
            mx = fmaxf(mx, __shfl_xor(mx, 1, 64));
            mx = fmaxf(mx, __shfl_xor(mx, 2, 64));
            mx = fmaxf(mx, __shfl_xor(mx, 4, 64));
            float inv = (mx > 0.f) ? 127.f / mx : 0.f;
            unsigned pk[8];
#pragma unroll
            for (int w2 = 0; w2 < 8; ++w2) {
                unsigned p = 0;
#pragma unroll
                for (int b = 0; b < 4; ++b) {
                    int e8 = w2 * 4 + b;
                    float v = bf2f(e[e8 >> 3][e8 & 7]);
                    int qv = (int)rintf(v * inv);
                    p |= ((unsigned)(qv & 255)) << (8 * b);
                }
                pk[w2] = p;
            }
            if (rr < M) {
                uint4* dst = (uint4*)&Cq[(size_t)rr * 256 + ch8 * 32];
                dst[0] = make_uint4(pk[0], pk[1], pk[2], pk[3]);
                dst[1] = make_uint4(pk[4], pk[5], pk[6], pk[7]);
                if (ch8 == 0) csc[rr] = mx * (1.f / 127.f);
            }
        } else {
            // fused mean-pool: per-column run-length walk over 32 rows, atomic flush
            int c = tid & 255, hh = tid >> 8;
            int gcur = sbatch[hh * 32];
            float acp = 0.f;
#pragma unroll 1
            for (int r = 0; r < 32; ++r) {
                int gb = sbatch[hh * 32 + r];
                if (gb != gcur) {
                    if (gcur >= 0) atomicAdd(&HGacc[(size_t)gcur * 256 + c], acp);
                    acp = 0.f; gcur = gb;
                }
                if (gb >= 0) acp += bf2f(Et[(hh * 32 + r) * 264 + c]);
            }
            if (gcur >= 0) atomicAdd(&HGacc[(size_t)gcur * 256 + c], acp);
        }
    }
}

// ---------- MLP head: A from HGacc f32 (scale by 1/cnt, cast) ; rest as before ----------
__global__ __launch_bounds__(256) void mlp_head_k(const float* __restrict__ HGacc,
                                                  const int* __restrict__ gstart,
                                                  const unsigned short* __restrict__ Wf1t,  // [128][256]
                                                  const unsigned short* __restrict__ Wf2t,  // [32][128]
                                                  const float* __restrict__ bf1, const float* __restrict__ bf2,
                                                  float* __restrict__ out) {
    __shared__ unsigned short As1[128 * 32];   // 8 KB
    __shared__ unsigned short Bs1[128 * 32];   // 8 KB
    __shared__ unsigned short R[128 * 128];    // 32 KB
    __shared__ unsigned short Bs2[32 * 128];   // 8 KB
    __shared__ float invc[128];
    const int tid = threadIdx.x;
    const int lane = tid & 63, wave = tid >> 6;
    const int m = lane & 15, q = lane >> 4;
    const int rowBase = blockIdx.x * 128;
    const int wr = (wave >> 1) * 64;
    const int wc = (wave & 1) * 64;

#pragma unroll
    for (int c2 = 0; c2 < 2; ++c2) {
        const unsigned short* g = &Wf2t[(c2 * 256 + tid) * 8];
        __builtin_amdgcn_global_load_lds((gas_ptr)g, (las_ptr)&Bs2[(c2 * 256 + wave * 64) * 8], 16, 0, 0);
    }
    if (tid < 128) {
        int g0 = rowBase + tid;
        invc[tid] = 1.f / fmaxf((float)(gstart[g0 + 1] - gstart[g0]), 1.f);
    }
    __syncthreads();

    f32x4 acc[4][4] = {};
    for (int kt = 0; kt < 256; kt += 32) {
        {   // A-staging: f32 mean -> bf16, via registers + ds_write
            int row = tid >> 1, half = tid & 1;
            const float4* src = (const float4*)&HGacc[(size_t)(rowBase + row) * 256 + kt + half * 16];
            float4 f0 = src[0], f1 = src[1], f2 = src[2], f3 = src[3];
            float sc = invc[row];
            ushort8v p0 = { f2bf(f0.x * sc), f2bf(f0.y * sc), f2bf(f0.z * sc), f2bf(f0.w * sc),
                            f2bf(f1.x * sc), f2bf(f1.y * sc), f2bf(f1.z * sc), f2bf(f1.w * sc) };
            ushort8v p1 = { f2bf(f2.x * sc), f2bf(f2.y * sc), f2bf(f2.z * sc), f2bf(f2.w * sc),
                            f2bf(f3.x * sc), f2bf(f3.y * sc), f2bf(f3.z * sc), f2bf(f3.w * sc) };
            *(ushort8v*)&As1[row * 32 + half * 16] = p0;
            *(ushort8v*)&As1[row * 32 + half * 16 + 8] = p1;
        }
#pragma unroll
        for (int c2 = 0; c2 < 2; ++c2) {
            int u = c2 * 256 + tid;
            int row = u >> 2, kp = u & 3;
            const unsigned short* gb = &Wf1t[(size_t)row * 256 + kt + kp * 8];
            __builtin_amdgcn_global_load_lds((gas_ptr)gb, (las_ptr)&Bs1[(c2 * 256 + wave * 64) * 8], 16, 0, 0);
        }
        __syncthreads();
        bf16x8 af[4], bfr[4];
#pragma unroll
        for (int i = 0; i < 4; ++i) af[i] = *(const bf16x8*)&As1[(wr + i * 16 + m) * 32 + q * 8];
#pragma unroll
        for (int j = 0; j < 4; ++j) bfr[j] = *(const bf16x8*)&Bs1[(wc + j * 16 + m) * 32 + q * 8];
#pragma unroll
        for (int i = 0; i < 4; ++i)
#pragma unroll
            for (int j = 0; j < 4; ++j)
                acc[i][j] = __builtin_amdgcn_mfma_f32_16x16x32_bf16(af[i], bfr[j], acc[i][j], 0, 0, 0);
        __syncthreads();
    }
#pragma unroll
    for (int i = 0; i < 4; ++i)
#pragma unroll
        for (int j = 0; j < 4; ++j) {
            int c = wc + j * 16 + m;
            float bv = bf1[c];
#pragma unroll
            for (int r = 0; r < 4; ++r) {
                int rr = wr + i * 16 + q * 4 + r;
                R[rr * 128 + c] = f2bf(fmaxf(acc[i][j][r] + bv, 0.f));
            }
        }
    __syncthreads();

    const int wr2 = wave * 32;
    f32x4 acc2[2][2] = {};
#pragma unroll
    for (int s2 = 0; s2 < 4; ++s2) {
        bf16x8 af2[2], bf22[2];
#pragma unroll
        for (int i = 0; i < 2; ++i) af2[i] = *(const bf16x8*)&R[(wr2 + i * 16 + m) * 128 + s2 * 32 + q * 8];
#pragma unroll
        for (int ct = 0; ct < 2; ++ct) bf22[ct] = *(const bf16x8*)&Bs2[(ct * 16 + m) * 128 + s2 * 32 + q * 8];
#pragma unroll
        for (int i = 0; i < 2; ++i)
#pragma unroll
            for (int ct = 0; ct < 2; ++ct)
                acc2[i][ct] = __builtin_amdgcn_mfma_f32_16x16x32_bf16(af2[i], bf22[ct], acc2[i][ct], 0, 0, 0);
    }
#pragma unroll
    for (int i = 0; i < 2; ++i)
#pragma unroll
        for (int ct = 0; ct < 2; ++ct) {
            int c = ct * 16 + m;
            float bv = bf2[c];
#pragma unroll
            for (int r = 0; r < 4; ++r) {
                int rr = rowBase + wr2 + i * 16 + q * 4 + r;
                out[(size_t)rr * 32 + c] = acc2[i][ct][r] + bv;
            }
        }
}

extern "C" void kernel_launch(void* const* d_in, const int* in_sizes, int n_in,
                              void* d_out, int out_size, void* d_ws, size_t ws_size,
                              hipStream_t stream) {
    const float* x    = (const float*)d_in[0];
    const int*   ei   = (const int*)d_in[1];
    const int*   batch= (const int*)d_in[2];
    const float* W1   = (const float*)d_in[3];
    const float* b1   = (const float*)d_in[4];
    const float* W2   = (const float*)d_in[5];
    const float* b2   = (const float*)d_in[6];
    const float* W3   = (const float*)d_in[7];
    const float* b3   = (const float*)d_in[8];
    const float* Wf1  = (const float*)d_in[9];
    const float* bf1  = (const float*)d_in[10];
    const float* Wf2  = (const float*)d_in[11];
    const float* bf2  = (const float*)d_in[12];
    float* out = (float*)d_out;

    const int* e_src = ei;
    const int* e_dst = ei + NEDGES;

    char* ws = (char*)d_ws;
    size_t off = 0;
    auto alloc = [&](size_t bytes) -> void* {
        void* p = (void*)(ws + off);
        off += (bytes + 255) & ~(size_t)255;
        return p;
    };
    unsigned char*  Xq  = (unsigned char*)alloc((size_t)NROWS * NFEAT);        // int8 input rows
    float*          xsc = (float*)alloc((size_t)NROWS * 4);                    // input row scales
    unsigned short* Za  = (unsigned short*)alloc((size_t)NROWS * NFEAT * 2);   // agg out, layer 1
    unsigned short* Zb  = (unsigned short*)alloc((size_t)NROWS * NHID * 2);    // agg out, layers 2-3
    unsigned char*  Hq  = (unsigned char*)alloc((size_t)NROWS * NHID);         // int8 activations
    float*          csc = (float*)alloc((size_t)NROWS * 4);                    // row scales
    float*          HGacc = (float*)alloc((size_t)NGRAPH * NHID * 4);          // pooled sums (f32)
    unsigned short* Wt1 = (unsigned short*)alloc((size_t)NHID * NFEAT * 2);    // sliced [4][256][32]
    unsigned short* Wt2 = (unsigned short*)alloc((size_t)NHID * NHID * 2);     // sliced [8][256][32]
    unsigned short* Wt3 = (unsigned short*)alloc((size_t)NHID * NHID * 2);     // sliced [8][256][32]
    unsigned short* Wf1t= (unsigned short*)alloc((size_t)NFEAT * NHID * 2);
    unsigned short* Wf2t= (unsigned short*)alloc((size_t)DOUT * NFEAT * 2);
    float* dinv = (float*)alloc((size_t)NNODES * 4);
    int*   cnt  = (int*)alloc((size_t)NNODES * 4);
    int*   fill = (int*)alloc((size_t)NNODES * 4);
    int*   rowp = (int*)alloc((size_t)(NNODES + 1) * 4);   // pre-offset
    int*   rowf = (int*)alloc((size_t)(NNODES + 1) * 4);   // finalized
    int2*  adj8 = (int2*)alloc((size_t)NNODES * 8 * 8);    // inline slots {src, norm} x8
    int2*  adj  = (int2*)alloc((size_t)NEDGES * 8);        // CSR overflow (entries >= 8)
    int2*  hdr  = (int2*)alloc((size_t)NNODES * 8);        // {deg, dinv^2}
    int*   part = (int*)alloc((size_t)64 * 4);
    int*   gstart = (int*)alloc((size_t)(NGRAPH + 1) * 4);
    (void)alloc(131072);   // tail pad

    const int nb = (NNODES + 1023) / 1024;   // 49

    // ---- prep: x quant + weight casts + zero cnt/fill/adj8/HGacc ----
    hipLaunchKernelGGL(prep_k, dim3((1381776 + 255) / 256), dim3(256), 0, stream,
                       x, Xq, xsc, W1, W2, W3, Wf1, Wf2, Wt1, Wt2, Wt3, Wf1t, Wf2t, cnt, fill,
                       (int4*)adj8, (float4*)HGacc);
    // ---- CSR + slots + norm + graph starts ----
    hipLaunchKernelGGL(edge_hist_k, dim3((NEDGES + 255) / 256), dim3(256), 0, stream, e_dst, cnt, NEDGES);
    hipLaunchKernelGGL(scan_block_k, dim3(nb), dim3(1024), 0, stream, cnt, rowp, part, dinv, hdr, NNODES);
    hipLaunchKernelGGL(scatter_k, dim3((NEDGES + 255) / 256), dim3(256), 0, stream,
                       e_src, e_dst, rowp, part, fill, dinv, adj8, adj, rowf, batch, gstart,
                       NEDGES, NNODES, nb);

    const int ntiles = NROWS / 64;          // 782
    // ---- layer 1: Za = A_hat Xq (int8 gather); Hq,csc = q8(relu(Za@W1+b1)) ----
    hipLaunchKernelGGL(agg_q1_k, dim3((NNODES + 15) / 16), dim3(256), 0, stream,
                       Xq, xsc, (const int4*)adj8, hdr, rowf, adj, Za, NNODES);
    hipLaunchKernelGGL((gemm_k<128, 1>), dim3(512), dim3(512), 0, stream,
                       Za, Wt1, b1, Hq, csc, (float*)nullptr, (const int*)nullptr, NNODES, 3, ntiles);
    // ---- layer 2: Zb = A_hat Hq (int8 gather); Hq,csc = q8(relu(Zb@W2+b2)) ----
    hipLaunchKernelGGL(agg_q_k, dim3((NNODES + 7) / 8), dim3(256), 0, stream,
                       Hq, csc, (const int4*)adj8, hdr, rowf, adj, Zb, NNODES);
    hipLaunchKernelGGL((gemm_k<256, 1>), dim3(512), dim3(512), 0, stream,
                       Zb, Wt2, b2, Hq, csc, (float*)nullptr, (const int*)nullptr, NNODES, 3, ntiles);
    // ---- layer 3: Zb = A_hat Hq; relu(Zb@W3+b3) pooled directly into HGacc ----
    hipLaunchKernelGGL(agg_q_k, dim3((NNODES + 7) / 8), dim3(256), 0, stream,
                       Hq, csc, (const int4*)adj8, hdr, rowf, adj, Zb, NNODES);
    hipLaunchKernelGGL((gemm_k<256, 2>), dim3(512), dim3(512), 0, stream,
                       Zb, Wt3, b3, (unsigned char*)nullptr, (float*)nullptr, HGacc, batch, NNODES, 3, ntiles);

    // ---- MLP head (mean + cast fused into A-staging) ----
    hipLaunchKernelGGL(mlp_head_k, dim3(NGRAPH / 128), dim3(256), 0, stream,
                       HGacc, gstart, Wf1t, Wf2t, bf1, bf2, out);
}

// Round 7
// 251.969 us; speedup vs baseline: 1.0938x; 1.0910x over previous
//
#include <hip/hip_runtime.h>
#include <hip/hip_bf16.h>

#define NNODES 50000
#define NEDGES 300000
#define NGRAPH 2048
#define NFEAT  128
#define NHID   256
#define DOUT   32
#define NROWS  50048   // 64-aligned row allocation

typedef __bf16 bf16x8 __attribute__((ext_vector_type(8)));
typedef float  f32x4  __attribute__((ext_vector_type(4)));
typedef int    i32x4  __attribute__((ext_vector_type(4)));
typedef unsigned short ushort8v __attribute__((ext_vector_type(8)));
typedef __attribute__((address_space(1))) const void* gas_ptr;
typedef __attribute__((address_space(3))) void* las_ptr;

__device__ __forceinline__ float bf2f(unsigned short u) {
    return __uint_as_float(((unsigned)u) << 16);
}
__device__ __forceinline__ unsigned short f2bf(float f) {
    unsigned u = __float_as_uint(f);
    unsigned r = u + 0x7FFFu + ((u >> 16) & 1u);   // RNE
    return (unsigned short)(r >> 16);
}
__device__ __forceinline__ float sb2f(unsigned v, int k) {   // signed byte k of word -> float
    return (float)((signed char)(v >> (8 * k)));
}

// W8A8 pipeline: aggregation outputs per-row int8 + scale (asc); weights are per-column
// int8 + scale (bsc, sliced [k/64][n][64B] to match the i8 MFMA fragment); GEMM runs
// v_mfma_i32_16x16x64_i8 with exact int32 accumulate, dequant in the epilogue.
// Z arrays (Za8/Zb8) are XOR-swizzled in 16B chunks (ch ^= row&7) so linear
// global_load_lds staging yields conflict-free swizzled ds_read_b128.

// ---------- weight per-column int8 quant helper (16 threads/col, col n = t>>4) ----------
template<int K>
__device__ __forceinline__ void wquant(const float* __restrict__ W, unsigned char* __restrict__ Wq,
                                       float* __restrict__ bsc, int t) {
    constexpr int EPR = K / 16;               // elems per thread (8 or 16)
    int n = t >> 4, p = t & 15;
    float vals[EPR];
    float mx = 0.f;
#pragma unroll
    for (int j = 0; j < EPR; ++j) {
        float v = W[(size_t)(p * EPR + j) * 256 + n];   // W is [K][256] row-major
        vals[j] = v;
        mx = fmaxf(mx, fabsf(v));
    }
    mx = fmaxf(mx, __shfl_xor(mx, 1, 16));
    mx = fmaxf(mx, __shfl_xor(mx, 2, 16));
    mx = fmaxf(mx, __shfl_xor(mx, 4, 16));
    mx = fmaxf(mx, __shfl_xor(mx, 8, 16));
    float inv = (mx > 0.f) ? 127.f / mx : 0.f;
#pragma unroll
    for (int j4 = 0; j4 < EPR / 4; ++j4) {
        unsigned pw = 0;
#pragma unroll
        for (int b = 0; b < 4; ++b) {
            int qv = (int)rintf(vals[j4 * 4 + b] * inv);
            pw |= ((unsigned)(qv & 255)) << (8 * b);
        }
        int k = p * EPR + j4 * 4;
        *(unsigned*)&Wq[(k >> 6) * 16384 + n * 64 + (k & 63)] = pw;   // sliced [k/64][n][64]
    }
    if (p == 0) bsc[n] = mx * (1.f / 127.f);
}

// ---------- prep: x -> bf16 swizzled; W1-3 -> int8 col-quant; Wf -> bf16; zero cnt/fill/adj8 ----
__global__ __launch_bounds__(256) void prep_k(const float* __restrict__ x, unsigned short* __restrict__ x16,
                                              const float* __restrict__ W1, const float* __restrict__ W2,
                                              const float* __restrict__ W3, const float* __restrict__ Wf1,
                                              const float* __restrict__ Wf2,
                                              unsigned char* __restrict__ Wq1, unsigned char* __restrict__ Wq2,
                                              unsigned char* __restrict__ Wq3,
                                              float* __restrict__ bsc1, float* __restrict__ bsc2,
                                              float* __restrict__ bsc3,
                                              unsigned short* __restrict__ Wf1t, unsigned short* __restrict__ Wf2t,
                                              int* __restrict__ cnt, int* __restrict__ fill,
                                              int4* __restrict__ adj8z) {
    int idx = blockIdx.x * 256 + threadIdx.x;
    if (idx < 800000) {                       // x cast, one 16B chunk/thread, swizzled store
        int i = idx * 8;
        float4 a = *(const float4*)&x[i];
        float4 b = *(const float4*)&x[i + 4];
        ushort8v o = { f2bf(a.x), f2bf(a.y), f2bf(a.z), f2bf(a.w),
                       f2bf(b.x), f2bf(b.y), f2bf(b.z), f2bf(b.w) };
        int row = idx >> 4, ch = idx & 15;
        ((ushort8v*)x16)[(size_t)(row << 4) | (ch ^ (row & 7))] = o;
        return;
    }
    int t = idx - 800000;
    if (t < 4096)  { wquant<128>(W1, Wq1, bsc1, t); return; }
    t -= 4096;
    if (t < 4096)  { wquant<256>(W2, Wq2, bsc2, t); return; }
    t -= 4096;
    if (t < 4096)  { wquant<256>(W3, Wq3, bsc3, t); return; }
    t -= 4096;
    if (t < 36864) {   // Wf1t (32768) + Wf2t (4096), bf16 row-major [n][K]
        const float* W; unsigned short* Wt; int K, N;
        if (t < 32768) { W = Wf1; Wt = Wf1t; K = 256; N = 128; }
        else           { W = Wf2; Wt = Wf2t; K = 128; N = 32; t -= 32768; }
        int n = t / K, k = t - n * K;
        Wt[t] = f2bf(W[(size_t)k * N + n]);
        return;
    }
    t -= 36864;
    if (t < NNODES) { cnt[t] = 0; fill[t] = 0; return; }
    t -= NNODES;
    if (t < 200000) { int4 z4 = {0, 0, 0, 0}; adj8z[t] = z4; }   // zero inline slots
}

__global__ __launch_bounds__(256) void edge_hist_k(const int* __restrict__ dst, int* cnt, int E) {
    int e = blockIdx.x * 256 + threadIdx.x;
    if (e < E) atomicAdd(&cnt[dst[e]], 1);
}

// block-level scan + dinv + node header {deg, dinv^2} (chunk = 1024 nodes)
__global__ __launch_bounds__(1024) void scan_block_k(const int* __restrict__ cnt, int* __restrict__ rowp,
                                                     int* __restrict__ part, float* __restrict__ dinv,
                                                     int2* __restrict__ hdr, int n) {
    __shared__ int s[1024];
    int tid = threadIdx.x;
    int i = blockIdx.x * 1024 + tid;
    int v = (i < n) ? cnt[i] : 0;
    if (i < n) {
        float dv = rsqrtf((float)(v + 1));   // +1 self-loop
        dinv[i] = dv;
        hdr[i] = make_int2(v, __float_as_int(dv * dv));
    }
    s[tid] = v;
    __syncthreads();
    for (int off = 1; off < 1024; off <<= 1) {
        int t = (tid >= off) ? s[tid - off] : 0;
        __syncthreads();
        s[tid] += t;
        __syncthreads();
    }
    if (i < n) rowp[i] = s[tid] - v;               // exclusive, pre-offset
    if (tid == 1023) part[blockIdx.x] = s[1023];
}

// scatter: first 8 edges/dst -> inline slots adj8; rest -> CSR adj (entries >=8 only).
// rowp only read on the rare overflow path. Also finalizes rowp + graph-start table.
__global__ __launch_bounds__(256) void scatter_k(const int* __restrict__ src, const int* __restrict__ dst,
                                                 const int* __restrict__ rowp_pre, const int* __restrict__ part,
                                                 int* fill, const float* __restrict__ dinv,
                                                 int2* __restrict__ adj8, int2* __restrict__ adj,
                                                 int* __restrict__ rowp_fin,
                                                 const int* __restrict__ batch, int* __restrict__ gstart,
                                                 int E, int n, int nb) {
    __shared__ int s[64];
    int tid = threadIdx.x;
    if (tid < 64) s[tid] = (tid < nb) ? part[tid] : 0;
    __syncthreads();
    for (int off = 1; off < 64; off <<= 1) {
        int t = 0;
        if (tid < 64 && tid >= off) t = s[tid - off];
        __syncthreads();
        if (tid < 64) s[tid] += t;
        __syncthreads();
    }
    int gid = blockIdx.x * 256 + tid;
    if (gid <= n) {
        if (gid < n) {
            int ch = gid >> 10;
            int base = (ch == 0) ? 0 : s[ch - 1];
            rowp_fin[gid] = rowp_pre[gid] + base;
        } else {
            rowp_fin[n] = s[nb - 1];
        }
    }
    if (gid < n) {   // graph start offsets: gstart[g] = first node with batch >= g
        int b = batch[gid];
        int prev = (gid == 0) ? -1 : batch[gid - 1];
        for (int g = prev + 1; g <= b; ++g) gstart[g] = gid;
        if (gid == n - 1)
            for (int g = b + 1; g <= NGRAPH; ++g) gstart[g] = n;
    }
    if (gid < E) {
        int ss = src[gid], d = dst[gid];
        int f = atomicAdd(&fill[d], 1);
        int2 a; a.x = ss; a.y = __float_as_int(dinv[ss] * dinv[d]);
        if (f < 8) {
            adj8[d * 8 + f] = a;
        } else {
            int ch = d >> 10;
            int base = (ch == 0) ? 0 : s[ch - 1];
            adj[rowp_pre[d] + base + f] = a;
        }
    }
}

// ---------- layer-1 aggregation: bf16 X source, 16 lanes/node, int8+scale output ----------
__global__ __launch_bounds__(256) void agg1_k(const unsigned short* __restrict__ T,
                                              const int4* __restrict__ adj8,
                                              const int2* __restrict__ hdr,
                                              const int* __restrict__ rowf,
                                              const int2* __restrict__ adj,
                                              unsigned char* __restrict__ z8,
                                              float* __restrict__ asc, int n) {
    int g  = threadIdx.x >> 4;
    int li = threadIdx.x & 15;
    int node = blockIdx.x * 16 + g;
    if (node >= n) return;
    const ushort8v* tp = (const ushort8v*)T;
    int2 h = hdr[node];
    int deg = h.x;
    float sw = __int_as_float(h.y);
    ushort8v u = tp[(size_t)node * 16 + (li ^ (node & 7))];
    int4 s4[4];
#pragma unroll
    for (int j = 0; j < 4; ++j) s4[j] = adj8[node * 4 + j];
    float ac[8];
#pragma unroll
    for (int k = 0; k < 8; ++k) ac[k] = bf2f(u[k]) * sw;
    int c[8]; float w[8];
#pragma unroll
    for (int j = 0; j < 4; ++j) {
        c[2 * j]     = s4[j].x; w[2 * j]     = __int_as_float(s4[j].y);
        c[2 * j + 1] = s4[j].z; w[2 * j + 1] = __int_as_float(s4[j].w);
    }
    ushort8v mm[8];
#pragma unroll
    for (int j = 0; j < 8; ++j) mm[j] = tp[(size_t)c[j] * 16 + (li ^ (c[j] & 7))];
#pragma unroll
    for (int j = 0; j < 8; ++j)
#pragma unroll
        for (int k = 0; k < 8; ++k)
            ac[k] += bf2f(mm[j][k]) * w[j];
    if (deg > 8) {   // overflow: CSR entries >= 8
        int e0 = rowf[node], e1 = e0 + deg;
        for (int e = e0 + 8; e < e1; e += 4) {
            int2 a2[4];
#pragma unroll
            for (int j = 0; j < 4; ++j) {
                int ee = e + j;
                a2[j] = (ee < e1) ? adj[ee] : make_int2(0, 0);
            }
            ushort8v m2[4];
#pragma unroll
            for (int j = 0; j < 4; ++j) m2[j] = tp[(size_t)a2[j].x * 16 + (li ^ (a2[j].x & 7))];
#pragma unroll
            for (int j = 0; j < 4; ++j)
#pragma unroll
                for (int k = 0; k < 8; ++k)
                    ac[k] += bf2f(m2[j][k]) * __int_as_float(a2[j].y);
        }
    }
    // quantize row to int8 (rowmax over 16 lanes)
    float mx = 0.f;
#pragma unroll
    for (int k = 0; k < 8; ++k) mx = fmaxf(mx, fabsf(ac[k]));
    mx = fmaxf(mx, __shfl_xor(mx, 1, 16));
    mx = fmaxf(mx, __shfl_xor(mx, 2, 16));
    mx = fmaxf(mx, __shfl_xor(mx, 4, 16));
    mx = fmaxf(mx, __shfl_xor(mx, 8, 16));
    float inv = (mx > 0.f) ? 127.f / mx : 0.f;
    unsigned w0 = 0, w1 = 0;
#pragma unroll
    for (int k = 0; k < 4; ++k) {
        int q0 = (int)rintf(ac[k] * inv);
        int q1 = (int)rintf(ac[k + 4] * inv);
        w0 |= ((unsigned)(q0 & 255)) << (8 * k);
        w1 |= ((unsigned)(q1 & 255)) << (8 * k);
    }
    // swizzled store: row = 128B = 8 x 16B chunks; chunk = li>>1, half = li&1
    ((uint2*)z8)[(size_t)node * 16 + ((li >> 1) ^ (node & 7)) * 2 + (li & 1)] = make_uint2(w0, w1);
    if (li == 0) asc[node] = mx * (1.f / 127.f);
}

// ---------- layers 2-3 aggregation: int8 source (256B rows), 32 lanes/node, int8+scale out ----
__global__ __launch_bounds__(256) void agg_q_k(const unsigned char* __restrict__ Hq,
                                               const float* __restrict__ csc,
                                               const int4* __restrict__ adj8,
                                               const int2* __restrict__ hdr,
                                               const int* __restrict__ rowf,
                                               const int2* __restrict__ adj,
                                               unsigned char* __restrict__ z8,
                                               float* __restrict__ asc, int n) {
    int g  = threadIdx.x >> 5;
    int li = threadIdx.x & 31;
    int node = blockIdx.x * 8 + g;
    if (node >= n) return;
    const uint2* qp = (const uint2*)Hq;       // 8B chunks, 32 per row
    int2 h = hdr[node];
    int deg = h.x;
    float swgt = __int_as_float(h.y) * csc[node];
    uint2 u = qp[(size_t)node * 32 + li];
    int4 s4[4];
#pragma unroll
    for (int j = 0; j < 4; ++j) s4[j] = adj8[node * 4 + j];
    int c[8]; float w[8];
#pragma unroll
    for (int j = 0; j < 4; ++j) {
        c[2 * j]     = s4[j].x; w[2 * j]     = __int_as_float(s4[j].y);
        c[2 * j + 1] = s4[j].z; w[2 * j + 1] = __int_as_float(s4[j].w);
    }
    uint2 mm[8];
#pragma unroll
    for (int j = 0; j < 8; ++j) mm[j] = qp[(size_t)c[j] * 32 + li];
    float ws[8];
#pragma unroll
    for (int j = 0; j < 8; ++j) ws[j] = w[j] * csc[c[j]];
    float ac[8];
#pragma unroll
    for (int k = 0; k < 4; ++k) {
        ac[k]     = sb2f(u.x, k) * swgt;
        ac[k + 4] = sb2f(u.y, k) * swgt;
    }
#pragma unroll
    for (int j = 0; j < 8; ++j)
#pragma unroll
        for (int k = 0; k < 4; ++k) {
            ac[k]     += sb2f(mm[j].x, k) * ws[j];
            ac[k + 4] += sb2f(mm[j].y, k) * ws[j];
        }
    if (deg > 8) {   // overflow: CSR entries >= 8
        int e0 = rowf[node], e1 = e0 + deg;
        for (int e = e0 + 8; e < e1; e += 4) {
            int2 a2[4];
#pragma unroll
            for (int j = 0; j < 4; ++j) {
                int ee = e + j;
                a2[j] = (ee < e1) ? adj[ee] : make_int2(0, 0);
            }
            uint2 m2[4]; float w2[4];
#pragma unroll
            for (int j = 0; j < 4; ++j) m2[j] = qp[(size_t)a2[j].x * 32 + li];
#pragma unroll
            for (int j = 0; j < 4; ++j) w2[j] = __int_as_float(a2[j].y) * csc[a2[j].x];
#pragma unroll
            for (int j = 0; j < 4; ++j)
#pragma unroll
                for (int k = 0; k < 4; ++k) {
                    ac[k]     += sb2f(m2[j].x, k) * w2[j];
                    ac[k + 4] += sb2f(m2[j].y, k) * w2[j];
                }
        }
    }
    // quantize row to int8 (rowmax over 32 lanes)
    float mx = 0.f;
#pragma unroll
    for (int k = 0; k < 8; ++k) mx = fmaxf(mx, fabsf(ac[k]));
    mx = fmaxf(mx, __shfl_xor(mx, 1, 32));
    mx = fmaxf(mx, __shfl_xor(mx, 2, 32));
    mx = fmaxf(mx, __shfl_xor(mx, 4, 32));
    mx = fmaxf(mx, __shfl_xor(mx, 8, 32));
    mx = fmaxf(mx, __shfl_xor(mx, 16, 32));
    float inv = (mx > 0.f) ? 127.f / mx : 0.f;
    unsigned w0 = 0, w1 = 0;
#pragma unroll
    for (int k = 0; k < 4; ++k) {
        int q0 = (int)rintf(ac[k] * inv);
        int q1 = (int)rintf(ac[k + 4] * inv);
        w0 |= ((unsigned)(q0 & 255)) << (8 * k);
        w1 |= ((unsigned)(q1 & 255)) << (8 * k);
    }
    // swizzled store: row = 256B = 16 x 16B chunks; chunk = li>>1, half = li&1
    ((uint2*)z8)[(size_t)node * 32 + ((li >> 1) ^ (node & 7)) * 2 + (li & 1)] = make_uint2(w0, w1);
    if (li == 0) asc[node] = mx * (1.f / 127.f);
}

// ---------- W8A8 MFMA GEMM: DMA-staged swizzled int8 A-tile + register-stationary int8 B ----
// i8 MFMA 16x16x64 (2x bf16 rate, exact i32 accumulate). Dequant in epilogue:
// v = i32 * asc_row * bsc_col + bias. MODE 1: emit int8+scale (next gather);
// MODE 0: emit bf16 swizzled (for pool).
template<int K, int MODE>
__global__ __launch_bounds__(512, 2) void gemm_k(const unsigned char* __restrict__ A,
                                                 const unsigned char* __restrict__ Bq,
                                                 const float* __restrict__ bscale,
                                                 const float* __restrict__ asc,
                                                 const float* __restrict__ bias,
                                                 unsigned short* __restrict__ C,
                                                 unsigned char* __restrict__ Cq,
                                                 float* __restrict__ csc,
                                                 int M, int flags, int ntiles) {
    constexpr int CPR = K / 16;                // 16B chunks per row (8 or 16)
    constexpr int LP  = (64 * CPR) / 512;      // staging issues per thread (1 or 2)
    __shared__ unsigned char  At[64 * K];      // swizzled int8 A tile (8/16 KB)
    __shared__ unsigned short Et[64 * 264];    // epilogue tile (33.8 KB)
    __shared__ float sAsc[64];
    const int tid = threadIdx.x;
    const int lane = tid & 63;
    const int wave = tid >> 6;                 // 0..7
    const int m = lane & 15, q = lane >> 4;
    const int wr = (wave >> 2) * 32;           // 0 / 32
    const int wc = (wave & 3) * 64;            // 0 / 64 / 128 / 192

    // load this wave's int8 B slice (64 cols x K) into registers once
    i32x4 breg[K / 64][4];
#pragma unroll
    for (int kt = 0; kt < K / 64; ++kt)
#pragma unroll
        for (int j = 0; j < 4; ++j)
            breg[kt][j] = *(const i32x4*)&Bq[kt * 16384 + (wc + j * 16 + m) * 64 + q * 16];

    for (int t = blockIdx.x; t < ntiles; t += gridDim.x) {
        const size_t cbase = (size_t)t * 64 * K;   // tile base (bytes)
        // stage A-tile: linear byte copy of the pre-swizzled int8 rows
#pragma unroll
        for (int p = 0; p < LP; ++p) {
            int u = p * 512 + tid;
            __builtin_amdgcn_global_load_lds((gas_ptr)(A + cbase + (size_t)u * 16),
                                             (las_ptr)&At[(p * 512 + wave * 64) * 16], 16, 0, 0);
        }
        if (tid < 64) sAsc[tid] = asc[t * 64 + tid];
        __syncthreads();   // staging + sAsc complete (orders vs prev tile's At/Et use)

        i32x4 acc[2][4] = {};
#pragma unroll
        for (int kt = 0; kt < K / 64; ++kt) {
            i32x4 af[2];
#pragma unroll
            for (int i = 0; i < 2; ++i) {
                int lr = wr + i * 16 + m;
                af[i] = *(const i32x4*)&At[lr * K + (((kt * 4 + q) ^ (lr & 7)) * 16)];
            }
#pragma unroll
            for (int i = 0; i < 2; ++i)
#pragma unroll
                for (int j = 0; j < 4; ++j)
                    acc[i][j] = __builtin_amdgcn_mfma_i32_16x16x64_i8(af[i], breg[kt][j], acc[i][j], 0, 0, 0);
        }

        // epilogue: dequant + bias + relu, repack to Et (bf16)
#pragma unroll
        for (int i = 0; i < 2; ++i) {
#pragma unroll
            for (int j = 0; j < 4; ++j) {
                int c = wc + j * 16 + m;
                float bv = (flags & 2) ? bias[c] : 0.f;
                float bs = bscale[c];
#pragma unroll
                for (int r = 0; r < 4; ++r) {
                    int row = wr + i * 16 + q * 4 + r;
                    float v = (float)acc[i][j][r] * (sAsc[row] * bs) + bv;
                    if (flags & 1) v = fmaxf(v, 0.f);
                    Et[row * 264 + c] = f2bf(v);
                }
            }
        }
        __syncthreads();   // Et ready; all At/sAsc reads this tile complete

        if (MODE == 1) {
            // per-row int8 quantization: 8 threads/row, 32 elems/thread
            int row = tid >> 3, ch8 = tid & 7;
            int rr = t * 64 + row;
            ushort8v e[4];
#pragma unroll
            for (int k2 = 0; k2 < 4; ++k2)
                e[k2] = *(const ushort8v*)&Et[row * 264 + ch8 * 32 + k2 * 8];
            float mx = 0.f;
#pragma unroll
            for (int k2 = 0; k2 < 4; ++k2)
#pragma unroll
                for (int k = 0; k < 8; ++k) mx = fmaxf(mx, fabsf(bf2f(e[k2][k])));
            mx = fmaxf(mx, __shfl_xor(mx, 1, 64));
            mx = fmaxf(mx, __shfl_xor(mx, 2, 64));
            mx = fmaxf(mx, __shfl_xor(mx, 4, 64));
            float inv = (mx > 0.f) ? 127.f / mx : 0.f;
            unsigned pk[8];
#pragma unroll
            for (int w2 = 0; w2 < 8; ++w2) {
                unsigned p = 0;
#pragma unroll
                for (int b = 0; b < 4; ++b) {
                    int e8 = w2 * 4 + b;
                    float v = bf2f(e[e8 >> 3][e8 & 7]);
                    int qv = (int)rintf(v * inv);
                    p |= ((unsigned)(qv & 255)) << (8 * b);
                }
                pk[w2] = p;
            }
            if (rr < M) {
                uint4* dst = (uint4*)&Cq[(size_t)rr * 256 + ch8 * 32];
                dst[0] = make_uint4(pk[0], pk[1], pk[2], pk[3]);
                dst[1] = make_uint4(pk[4], pk[5], pk[6], pk[7]);
                if (ch8 == 0) csc[rr] = mx * (1.f / 127.f);
            }
        } else {
            // coalesced swizzled bf16 stores (for pool)
#pragma unroll
            for (int u0 = 0; u0 < 4; ++u0) {
                int u = u0 * 512 + tid;
                int row = u >> 5, cc = u & 31;
                int rr = t * 64 + row;
                if (rr < M)
                    ((ushort8v*)C)[(size_t)rr * 32 + (cc ^ (rr & 7))] = *(const ushort8v*)&Et[row * 264 + cc * 8];
            }
        }
    }
}

// ---------- pooling: one block per graph, swizzled reads, gstart bounds ----------
__global__ __launch_bounds__(256) void pool_k(const unsigned short* __restrict__ h,
                                              const int* __restrict__ gstart,
                                              unsigned short* __restrict__ hg) {
    __shared__ float red[4][256];
    int g = blockIdx.x;
    int wave = threadIdx.x >> 6, lane = threadIdx.x & 63;
    int s = gstart[g], e = gstart[g + 1];
    int ch = lane >> 1, sub = lane & 1;
    const ushort4* hp = (const ushort4*)h;
    float4 acc = make_float4(0.f, 0.f, 0.f, 0.f);
    for (int i = s + wave; i < e; i += 4) {
        ushort4 v = hp[((size_t)i * 32 + (ch ^ (i & 7))) * 2 + sub];
        acc.x += bf2f(v.x); acc.y += bf2f(v.y); acc.z += bf2f(v.z); acc.w += bf2f(v.w);
    }
    *(float4*)&red[wave][lane * 4] = acc;
    __syncthreads();
    if (wave == 0) {
        float inv = 1.f / fmaxf((float)(e - s), 1.f);
        float v0 = red[0][lane*4+0] + red[1][lane*4+0] + red[2][lane*4+0] + red[3][lane*4+0];
        float v1 = red[0][lane*4+1] + red[1][lane*4+1] + red[2][lane*4+1] + red[3][lane*4+1];
        float v2 = red[0][lane*4+2] + red[1][lane*4+2] + red[2][lane*4+2] + red[3][lane*4+2];
        float v3 = red[0][lane*4+3] + red[1][lane*4+3] + red[2][lane*4+3] + red[3][lane*4+3];
        ushort4 o = { f2bf(v0 * inv), f2bf(v1 * inv), f2bf(v2 * inv), f2bf(v3 * inv) };
        ((ushort4*)(hg + (size_t)g * NHID))[lane] = o;
    }
}

// ---------- MLP head, fused: out = relu(HG@Wf1t^T + bf1) @ Wf2t^T + bf2 ----------
__global__ __launch_bounds__(256) void mlp_head_k(const unsigned short* __restrict__ HG,
                                                  const unsigned short* __restrict__ Wf1t,  // [128][256]
                                                  const unsigned short* __restrict__ Wf2t,  // [32][128]
                                                  const float* __restrict__ bf1, const float* __restrict__ bf2,
                                                  float* __restrict__ out) {
    __shared__ unsigned short As1[128 * 32];   // 8 KB
    __shared__ unsigned short Bs1[128 * 32];   // 8 KB
    __shared__ unsigned short R[128 * 128];    // 32 KB
    __shared__ unsigned short Bs2[32 * 128];   // 8 KB
    const int tid = threadIdx.x;
    const int lane = tid & 63, wave = tid >> 6;
    const int m = lane & 15, q = lane >> 4;
    const int rowBase = blockIdx.x * 128;
    const int wr = (wave >> 1) * 64;
    const int wc = (wave & 1) * 64;

#pragma unroll
    for (int c2 = 0; c2 < 2; ++c2) {
        const unsigned short* g = &Wf2t[(c2 * 256 + tid) * 8];
        __builtin_amdgcn_global_load_lds((gas_ptr)g, (las_ptr)&Bs2[(c2 * 256 + wave * 64) * 8], 16, 0, 0);
    }

    f32x4 acc[4][4] = {};
    for (int kt = 0; kt < 256; kt += 32) {
#pragma unroll
        for (int c2 = 0; c2 < 2; ++c2) {
            int u = c2 * 256 + tid;
            int row = u >> 2, kp = u & 3;
            const unsigned short* ga = &HG[(size_t)(rowBase + row) * 256 + kt + kp * 8];
            const unsigned short* gb = &Wf1t[(size_t)row * 256 + kt + kp * 8];
            __builtin_amdgcn_global_load_lds((gas_ptr)ga, (las_ptr)&As1[(c2 * 256 + wave * 64) * 8], 16, 0, 0);
            __builtin_amdgcn_global_load_lds((gas_ptr)gb, (las_ptr)&Bs1[(c2 * 256 + wave * 64) * 8], 16, 0, 0);
        }
        __syncthreads();
        bf16x8 af[4], bfr[4];
#pragma unroll
        for (int i = 0; i < 4; ++i) af[i] = *(const bf16x8*)&As1[(wr + i * 16 + m) * 32 + q * 8];
#pragma unroll
        for (int j = 0; j < 4; ++j) bfr[j] = *(const bf16x8*)&Bs1[(wc + j * 16 + m) * 32 + q * 8];
#pragma unroll
        for (int i = 0; i < 4; ++i)
#pragma unroll
            for (int j = 0; j < 4; ++j)
                acc[i][j] = __builtin_amdgcn_mfma_f32_16x16x32_bf16(af[i], bfr[j], acc[i][j], 0, 0, 0);
        __syncthreads();
    }
#pragma unroll
    for (int i = 0; i < 4; ++i)
#pragma unroll
        for (int j = 0; j < 4; ++j) {
            int c = wc + j * 16 + m;
            float bv = bf1[c];
#pragma unroll
            for (int r = 0; r < 4; ++r) {
                int rr = wr + i * 16 + q * 4 + r;
                R[rr * 128 + c] = f2bf(fmaxf(acc[i][j][r] + bv, 0.f));
            }
        }
    __syncthreads();

    const int wr2 = wave * 32;
    f32x4 acc2[2][2] = {};
#pragma unroll
    for (int s2 = 0; s2 < 4; ++s2) {
        bf16x8 af2[2], bf22[2];
#pragma unroll
        for (int i = 0; i < 2; ++i) af2[i] = *(const bf16x8*)&R[(wr2 + i * 16 + m) * 128 + s2 * 32 + q * 8];
#pragma unroll
        for (int ct = 0; ct < 2; ++ct) bf22[ct] = *(const bf16x8*)&Bs2[(ct * 16 + m) * 128 + s2 * 32 + q * 8];
#pragma unroll
        for (int i = 0; i < 2; ++i)
#pragma unroll
            for (int ct = 0; ct < 2; ++ct)
                acc2[i][ct] = __builtin_amdgcn_mfma_f32_16x16x32_bf16(af2[i], bf22[ct], acc2[i][ct], 0, 0, 0);
    }
#pragma unroll
    for (int i = 0; i < 2; ++i)
#pragma unroll
        for (int ct = 0; ct < 2; ++ct) {
            int c = ct * 16 + m;
            float bv = bf2[c];
#pragma unroll
            for (int r = 0; r < 4; ++r) {
                int rr = rowBase + wr2 + i * 16 + q * 4 + r;
                out[(size_t)rr * 32 + c] = acc2[i][ct][r] + bv;
            }
        }
}

extern "C" void kernel_launch(void* const* d_in, const int* in_sizes, int n_in,
                              void* d_out, int out_size, void* d_ws, size_t ws_size,
                              hipStream_t stream) {
    const float* x    = (const float*)d_in[0];
    const int*   ei   = (const int*)d_in[1];
    const int*   batch= (const int*)d_in[2];
    const float* W1   = (const float*)d_in[3];
    const float* b1   = (const float*)d_in[4];
    const float* W2   = (const float*)d_in[5];
    const float* b2   = (const float*)d_in[6];
    const float* W3   = (const float*)d_in[7];
    const float* b3   = (const float*)d_in[8];
    const float* Wf1  = (const float*)d_in[9];
    const float* bf1  = (const float*)d_in[10];
    const float* Wf2  = (const float*)d_in[11];
    const float* bf2  = (const float*)d_in[12];
    float* out = (float*)d_out;

    const int* e_src = ei;
    const int* e_dst = ei + NEDGES;

    char* ws = (char*)d_ws;
    size_t off = 0;
    auto alloc = [&](size_t bytes) -> void* {
        void* p = (void*)(ws + off);
        off += (bytes + 255) & ~(size_t)255;
        return p;
    };
    unsigned short* X16 = (unsigned short*)alloc((size_t)NROWS * NFEAT * 2);   // bf16 swizzled X
    unsigned char*  Za8 = (unsigned char*)alloc((size_t)NROWS * NFEAT);        // int8 agg out, layer 1
    unsigned char*  Zb8 = (unsigned char*)alloc((size_t)NROWS * NHID);         // int8 agg out, layers 2-3
    float*          asc = (float*)alloc((size_t)NROWS * 4);                    // agg row scales
    unsigned char*  Hq  = (unsigned char*)alloc((size_t)NROWS * NHID);         // int8 activations
    float*          csc = (float*)alloc((size_t)NROWS * 4);                    // activation row scales
    unsigned short* Ha  = (unsigned short*)alloc((size_t)NROWS * NHID * 2);    // gemm3 out (bf16)
    unsigned short* HG  = (unsigned short*)alloc((size_t)NGRAPH * NHID * 2);
    unsigned char*  Wq1 = (unsigned char*)alloc((size_t)NFEAT * NHID);         // int8 sliced [2][256][64]
    unsigned char*  Wq2 = (unsigned char*)alloc((size_t)NHID * NHID);          // int8 sliced [4][256][64]
    unsigned char*  Wq3 = (unsigned char*)alloc((size_t)NHID * NHID);          // int8 sliced [4][256][64]
    float*          bsc1= (float*)alloc((size_t)NHID * 4);
    float*          bsc2= (float*)alloc((size_t)NHID * 4);
    float*          bsc3= (float*)alloc((size_t)NHID * 4);
    unsigned short* Wf1t= (unsigned short*)alloc((size_t)NFEAT * NHID * 2);
    unsigned short* Wf2t= (unsigned short*)alloc((size_t)DOUT * NFEAT * 2);
    float* dinv = (float*)alloc((size_t)NNODES * 4);
    int*   cnt  = (int*)alloc((size_t)NNODES * 4);
    int*   fill = (int*)alloc((size_t)NNODES * 4);
    int*   rowp = (int*)alloc((size_t)(NNODES + 1) * 4);   // pre-offset
    int*   rowf = (int*)alloc((size_t)(NNODES + 1) * 4);   // finalized
    int2*  adj8 = (int2*)alloc((size_t)NNODES * 8 * 8);    // inline slots {src, norm} x8
    int2*  adj  = (int2*)alloc((size_t)NEDGES * 8);        // CSR overflow (entries >= 8)
    int2*  hdr  = (int2*)alloc((size_t)NNODES * 8);        // {deg, dinv^2}
    int*   part = (int*)alloc((size_t)64 * 4);
    int*   gstart = (int*)alloc((size_t)(NGRAPH + 1) * 4);
    (void)alloc(131072);   // tail pad

    const int nb = (NNODES + 1023) / 1024;   // 49
    const int nprep = 800000 + 4096 * 3 + 36864 + NNODES + 200000;   // 1,099,152

    // ---- prep: x cast + weight quant/casts + zero cnt/fill/adj8 ----
    hipLaunchKernelGGL(prep_k, dim3((nprep + 255) / 256), dim3(256), 0, stream,
                       x, X16, W1, W2, W3, Wf1, Wf2, Wq1, Wq2, Wq3, bsc1, bsc2, bsc3,
                       Wf1t, Wf2t, cnt, fill, (int4*)adj8);
    // ---- CSR + slots + norm + graph starts ----
    hipLaunchKernelGGL(edge_hist_k, dim3((NEDGES + 255) / 256), dim3(256), 0, stream, e_dst, cnt, NEDGES);
    hipLaunchKernelGGL(scan_block_k, dim3(nb), dim3(1024), 0, stream, cnt, rowp, part, dinv, hdr, NNODES);
    hipLaunchKernelGGL(scatter_k, dim3((NEDGES + 255) / 256), dim3(256), 0, stream,
                       e_src, e_dst, rowp, part, fill, dinv, adj8, adj, rowf, batch, gstart,
                       NEDGES, NNODES, nb);

    const int ntiles = NROWS / 64;          // 782
    // ---- layer 1: Za8,asc = q8(A_hat X); Hq,csc = q8(relu(deq(Za8@Wq1)+b1)) ----
    hipLaunchKernelGGL(agg1_k, dim3((NNODES + 15) / 16), dim3(256), 0, stream,
                       X16, (const int4*)adj8, hdr, rowf, adj, Za8, asc, NNODES);
    hipLaunchKernelGGL((gemm_k<128, 1>), dim3(512), dim3(512), 0, stream,
                       Za8, Wq1, bsc1, asc, b1, (unsigned short*)nullptr, Hq, csc, NNODES, 3, ntiles);
    // ---- layer 2 ----
    hipLaunchKernelGGL(agg_q_k, dim3((NNODES + 7) / 8), dim3(256), 0, stream,
                       Hq, csc, (const int4*)adj8, hdr, rowf, adj, Zb8, asc, NNODES);
    hipLaunchKernelGGL((gemm_k<256, 1>), dim3(512), dim3(512), 0, stream,
                       Zb8, Wq2, bsc2, asc, b2, (unsigned short*)nullptr, Hq, csc, NNODES, 3, ntiles);
    // ---- layer 3: bf16 output for pooling ----
    hipLaunchKernelGGL(agg_q_k, dim3((NNODES + 7) / 8), dim3(256), 0, stream,
                       Hq, csc, (const int4*)adj8, hdr, rowf, adj, Zb8, asc, NNODES);
    hipLaunchKernelGGL((gemm_k<256, 0>), dim3(512), dim3(512), 0, stream,
                       Zb8, Wq3, bsc3, asc, b3, Ha, (unsigned char*)nullptr, (float*)nullptr, NNODES, 3, ntiles);

    // ---- pool (one block/graph) ----
    hipLaunchKernelGGL(pool_k, dim3(NGRAPH), dim3(256), 0, stream, Ha, gstart, HG);

    // ---- MLP head (fused) ----
    hipLaunchKernelGGL(mlp_head_k, dim3(NGRAPH / 128), dim3(256), 0, stream,
                       HG, Wf1t, Wf2t, bf1, bf2, out);
}